// Round 2
// baseline (45571.982 us; speedup 1.0000x reference)
//
#include <hip/hip_runtime.h>
#include <hip/hip_cooperative_groups.h>

namespace cg = cooperative_groups;

#define BATCH 256
#define SEQL  512
#define DIN   256
#define DH    512
#define NG    2048   // 4*DH, gate-interleaved: col n = 4*unit + gate (0=g,1=i,2=f,3=o)
#define KTOT  768    // DIN + DH
#define BK    64
#define TM    64     // rows (batch) per block
#define TN    32     // gate-cols per block -> 8 complete units
#define NTH   512
#define NCHUNK (KTOT / BK)   // 12
#define NCLS  1024

#define APAD  1                       // stride 65: staging writes 2-way (free), reads conflict-free
#define WS_FLOATS (KTOT * TN)         // 24576 floats = 96 KB, resident whole kernel
#define AS_FLOATS (2 * BK * (TM + APAD))
#define SMEM_BYTES ((WS_FLOATS + AS_FLOATS) * 4)   // 132,096 B

// ---------------------------------------------------------------------------
// Pack weights into k-major [KTOT][NG] with gate-interleaved columns, pack
// biases, and zero the initial h buffer.
// ---------------------------------------------------------------------------
__global__ void pack_kernel(const float* __restrict__ Wgx, const float* __restrict__ Wgh,
                            const float* __restrict__ Wix, const float* __restrict__ Wih,
                            const float* __restrict__ Wfx, const float* __restrict__ Wfh,
                            const float* __restrict__ Wox, const float* __restrict__ Woh,
                            const float* __restrict__ bg,  const float* __restrict__ bi,
                            const float* __restrict__ bf,  const float* __restrict__ bo,
                            float* __restrict__ Wp, float* __restrict__ bp,
                            float* __restrict__ h0)
{
    int idx = blockIdx.x * blockDim.x + threadIdx.x;
    const int total = KTOT * NG;
    if (idx < total) {
        int k = idx / NG;
        int n = idx - k * NG;
        int unit = n >> 2;
        int gate = n & 3;
        float v;
        if (k < DIN) {
            const float* src = (gate == 0) ? Wgx : (gate == 1) ? Wix : (gate == 2) ? Wfx : Wox;
            v = src[k * DH + unit];
        } else {
            const float* src = (gate == 0) ? Wgh : (gate == 1) ? Wih : (gate == 2) ? Wfh : Woh;
            v = src[(k - DIN) * DH + unit];
        }
        Wp[idx] = v;
    }
    if (idx < NG) {
        int unit = idx >> 2;
        int gate = idx & 3;
        const float* bsrc = (gate == 0) ? bg : (gate == 1) ? bi : (gate == 2) ? bf : bo;
        bp[idx] = bsrc[unit];
    }
    if (idx < BATCH * DH) h0[idx] = 0.f;
}

// ---------------------------------------------------------------------------
// Persistent cooperative LSTM. 256 blocks x 512 threads (2 waves/SIMD).
// Block tile 64 rows x 32 gate-cols. W panel (768x32, 96 KB) resident in LDS
// for the entire kernel; only the A-tile is staged per step (double-buffered,
// ONE barrier per chunk). Thread micro-tile: 1 row x 4 cols = one unit; c is
// a register for all 512 steps. Next-step x prefetch issued before grid.sync.
// ---------------------------------------------------------------------------
__global__ __launch_bounds__(NTH, 2) void lstm_main(
    const float* __restrict__ x, const float* __restrict__ Wp,
    const float* __restrict__ bp, float* __restrict__ h0, float* __restrict__ h1)
{
    extern __shared__ float smem[];
    float* Ws = smem;                         // [KTOT][TN]
    float* As = smem + WS_FLOATS;             // [2][BK][TM+APAD]

    const int tid = threadIdx.x;
    const int bid = blockIdx.x;
    const int r0 = (bid & 3) * TM;            // 4 row tiles
    const int n0 = (bid >> 2) * TN;           // 64 col tiles
    const int tx = tid & 7;                   // unit within tile
    const int ty = tid >> 3;                  // row 0..63
    const int unit = (n0 >> 2) + tx;
    const int row = r0 + ty;

    // loader mapping: lk = k within chunk, rows lr+8i
    const int lk = tid & 63;
    const int lr = tid >> 6;                  // 0..7

    // resident W panel load (once)
    for (int idx = tid; idx < WS_FLOATS; idx += NTH) {
        int k = idx >> 5;                     // /TN
        int cc = idx & 31;
        Ws[idx] = Wp[(size_t)k * NG + n0 + cc];
    }

    const float b_g = bp[n0 + 4 * tx + 0];
    const float b_i = bp[n0 + 4 * tx + 1];
    const float b_f = bp[n0 + 4 * tx + 2];
    const float b_o = bp[n0 + 4 * tx + 3];

    float creg = 0.f;
    cg::grid_group grid = cg::this_grid();
    float* hb[2] = {h0, h1};

    // prologue: prefetch chunk 0 of t=0 (x part)
    float aPre[8];
    {
        const float* xb = x;   // t=0, kk=0
        #pragma unroll
        for (int i = 0; i < 8; ++i)
            aPre[i] = xb[(size_t)(r0 + lr + 8 * i) * (SEQL * DIN) + lk];
    }
    __syncthreads();   // Ws visible

    for (int t = 0; t < SEQL; ++t) {
        const float* __restrict__ hin = hb[t & 1];
        float* __restrict__ hout = hb[(t + 1) & 1];

        float a0 = 0.f, a1 = 0.f, a2 = 0.f, a3 = 0.f;

        for (int c = 0; c < NCHUNK; ++c) {
            // stage current chunk into buffer c&1
            float* dst = As + (c & 1) * (BK * (TM + APAD));
            #pragma unroll
            for (int i = 0; i < 8; ++i)
                dst[lk * (TM + APAD) + lr + 8 * i] = aPre[i];
            __syncthreads();

            // prefetch next chunk (or next step's chunk 0) into registers
            if (c + 1 < NCHUNK) {
                int kn = (c + 1) * BK;
                if (kn < DIN) {
                    const float* xb = x + (size_t)t * DIN + kn;
                    #pragma unroll
                    for (int i = 0; i < 8; ++i)
                        aPre[i] = xb[(size_t)(r0 + lr + 8 * i) * (SEQL * DIN) + lk];
                } else {
                    const float* hbp = hin + (kn - DIN);
                    #pragma unroll
                    for (int i = 0; i < 8; ++i)
                        aPre[i] = hbp[(size_t)(r0 + lr + 8 * i) * DH + lk];
                }
            } else if (t + 1 < SEQL) {
                const float* xb = x + (size_t)(t + 1) * DIN;
                #pragma unroll
                for (int i = 0; i < 8; ++i)
                    aPre[i] = xb[(size_t)(r0 + lr + 8 * i) * (SEQL * DIN) + lk];
            }

            // compute: 64 k-steps, W from resident LDS, A broadcast reads
            const float* as = As + (c & 1) * (BK * (TM + APAD));
            const float* wsb = Ws + c * (BK * TN);
            #pragma unroll
            for (int k = 0; k < BK; ++k) {
                float a = as[k * (TM + APAD) + ty];
                const float4 w = *(const float4*)&wsb[k * TN + 4 * tx];
                a0 += a * w.x; a1 += a * w.y; a2 += a * w.z; a3 += a * w.w;
            }
        }

        // gates + state update (reference quirk: sigmoid on g, tanh on i/f/o)
        float zg = a0 + b_g, zi = a1 + b_i, zf = a2 + b_f, zo = a3 + b_o;
        float gv = 1.0f / (1.0f + expf(-zg));
        float iv = tanhf(zi);
        float fv = tanhf(zf);
        float ov = tanhf(zo);
        creg = gv * iv + creg * fv;
        hout[(size_t)row * DH + unit] = tanhf(creg) * ov;

        grid.sync();
    }
}

// ---------------------------------------------------------------------------
// Final projection + softmax, fused. One block per batch row.
// ---------------------------------------------------------------------------
__global__ __launch_bounds__(256) void proj_softmax(
    const float* __restrict__ h, const float* __restrict__ Wph,
    const float* __restrict__ bP, float* __restrict__ out)
{
    __shared__ float red[256];
    const int r = blockIdx.x;
    const int tid = threadIdx.x;
    float a0 = 0.f, a1 = 0.f, a2 = 0.f, a3 = 0.f;
    const float* hr = h + (size_t)r * DH;
    for (int k = 0; k < DH; ++k) {
        float hv = hr[k];
        const float* w = Wph + (size_t)k * NCLS;
        a0 += hv * w[tid];
        a1 += hv * w[tid + 256];
        a2 += hv * w[tid + 512];
        a3 += hv * w[tid + 768];
    }
    a0 += bP[tid]; a1 += bP[tid + 256]; a2 += bP[tid + 512]; a3 += bP[tid + 768];

    float m = fmaxf(fmaxf(a0, a1), fmaxf(a2, a3));
    red[tid] = m; __syncthreads();
    for (int s = 128; s > 0; s >>= 1) {
        if (tid < s) red[tid] = fmaxf(red[tid], red[tid + s]);
        __syncthreads();
    }
    m = red[0];
    __syncthreads();

    float e0 = expf(a0 - m), e1 = expf(a1 - m), e2 = expf(a2 - m), e3 = expf(a3 - m);
    red[tid] = e0 + e1 + e2 + e3; __syncthreads();
    for (int s = 128; s > 0; s >>= 1) {
        if (tid < s) red[tid] += red[tid + s];
        __syncthreads();
    }
    const float inv = 1.0f / red[0];

    float* o = out + (size_t)r * NCLS;
    o[tid]       = e0 * inv;
    o[tid + 256] = e1 * inv;
    o[tid + 512] = e2 * inv;
    o[tid + 768] = e3 * inv;
}

// ---------------------------------------------------------------------------
extern "C" void kernel_launch(void* const* d_in, const int* in_sizes, int n_in,
                              void* d_out, int out_size, void* d_ws, size_t ws_size,
                              hipStream_t stream)
{
    const float* x   = (const float*)d_in[0];
    const float* Wgx = (const float*)d_in[1];
    const float* Wgh = (const float*)d_in[2];
    const float* bg  = (const float*)d_in[3];
    const float* Wix = (const float*)d_in[4];
    const float* Wih = (const float*)d_in[5];
    const float* bi  = (const float*)d_in[6];
    const float* Wfx = (const float*)d_in[7];
    const float* Wfh = (const float*)d_in[8];
    const float* bf  = (const float*)d_in[9];
    const float* Wox = (const float*)d_in[10];
    const float* Woh = (const float*)d_in[11];
    const float* bo  = (const float*)d_in[12];
    const float* Wph = (const float*)d_in[13];
    const float* bP  = (const float*)d_in[14];

    float* ws = (float*)d_ws;
    float* Wp = ws;                              // [768][2048]
    float* bp = Wp + (size_t)KTOT * NG;          // [2048]
    float* h0 = bp + NG;                         // [256][512]
    float* h1 = h0 + (size_t)BATCH * DH;         // [256][512]

    pack_kernel<<<(KTOT * NG + 255) / 256, 256, 0, stream>>>(
        Wgx, Wgh, Wix, Wih, Wfx, Wfh, Wox, Woh, bg, bi, bf, bo, Wp, bp, h0);

    hipFuncSetAttribute((const void*)lstm_main,
                        hipFuncAttributeMaxDynamicSharedMemorySize, SMEM_BYTES);

    void* args[] = {(void*)&x, (void*)&Wp, (void*)&bp, (void*)&h0, (void*)&h1};
    hipLaunchCooperativeKernel((void*)lstm_main, dim3(256), dim3(NTH), args,
                               SMEM_BYTES, stream);

    // final h is in h0 (512 steps -> buffer parity 0)
    proj_softmax<<<BATCH, 256, 0, stream>>>(h0, Wph, bP, (float*)d_out);
}

// Round 3
// 17953.168 us; speedup vs baseline: 2.5384x; 2.5384x over previous
//
#include <hip/hip_runtime.h>
#include <hip/hip_cooperative_groups.h>
#include <hip/hip_bf16.h>

namespace cg = cooperative_groups;

typedef __attribute__((ext_vector_type(4))) float f32x4;
typedef __attribute__((ext_vector_type(8))) short s16x8;   // 8 bf16 (4 VGPR) mfma frag
typedef __attribute__((ext_vector_type(4))) short s16x4;   // 4 bf16 (8B)

#define BATCH 256
#define SEQL  512
#define DIN   256
#define DH    512
#define NG    2048   // 4*DH, gate-interleaved: n = 4*unit + gate (0=g,1=i,2=f,3=o)
#define KTOT  768
#define NKT   24     // k-tiles of 32
#define NCLS  1024
#define NTH   512
#define ROWS  16     // batch rows per block
#define COLS  128    // gate cols per block
#define RSTR  776    // padded A_lds row stride (bf16 elems): 768+8 -> 2-way max conflicts

// bf16 RNE from f32, bit-twiddle (finite inputs)
__device__ __forceinline__ short bf16_rne(float a) {
    union { float f; unsigned u; } ua; ua.f = a;
    unsigned r = (ua.u + 0x7FFFu + ((ua.u >> 16) & 1u)) >> 16;
    return (short)r;
}
__device__ __forceinline__ float bf16_to_f32(short b) {
    union { unsigned u; float f; } v; v.u = ((unsigned)(unsigned short)b) << 16;
    return v.f;
}

// ---------------------------------------------------------------------------
// Pack W into hi/lo bf16 planes, n-major k-contiguous: Wb[n][k], n gate-
// interleaved. Pack biases (f32), zero h0.
// ---------------------------------------------------------------------------
__global__ void pack_kernel(const float* __restrict__ Wgx, const float* __restrict__ Wgh,
                            const float* __restrict__ Wix, const float* __restrict__ Wih,
                            const float* __restrict__ Wfx, const float* __restrict__ Wfh,
                            const float* __restrict__ Wox, const float* __restrict__ Woh,
                            const float* __restrict__ bg,  const float* __restrict__ bi,
                            const float* __restrict__ bf,  const float* __restrict__ bo,
                            short* __restrict__ Wb_hi, short* __restrict__ Wb_lo,
                            float* __restrict__ bp, float* __restrict__ h0)
{
    int idx = blockIdx.x * blockDim.x + threadIdx.x;
    if (idx < KTOT * NG) {
        int n = idx / KTOT;          // gate-col (consecutive idx -> consecutive k: coalesced writes)
        int k = idx - n * KTOT;
        int unit = n >> 2;
        int gate = n & 3;
        float v;
        if (k < DIN) {
            const float* src = (gate == 0) ? Wgx : (gate == 1) ? Wix : (gate == 2) ? Wfx : Wox;
            v = src[k * DH + unit];
        } else {
            const float* src = (gate == 0) ? Wgh : (gate == 1) ? Wih : (gate == 2) ? Wfh : Woh;
            v = src[(k - DIN) * DH + unit];
        }
        short hi = bf16_rne(v);
        short lo = bf16_rne(v - bf16_to_f32(hi));
        Wb_hi[idx] = hi;
        Wb_lo[idx] = lo;
    }
    if (idx < NG) {
        int unit = idx >> 2;
        int gate = idx & 3;
        const float* bsrc = (gate == 0) ? bg : (gate == 1) ? bi : (gate == 2) ? bf : bo;
        bp[idx] = bsrc[unit];
    }
    if (idx < BATCH * DH) h0[idx] = 0.f;
}

// ---------------------------------------------------------------------------
// Persistent split-bf16 MFMA LSTM. 256 blocks (16 row-tiles x 16 col-tiles)
// x 512 threads (8 waves). Block: 16 batch rows x 128 gate-cols; wave: 16x16
// out-tile (disjoint col sets). W frags (hi/lo) live in 192 VGPRs for the
// whole kernel. Per step: stage A=[x_t|h] rows to LDS as bf16 hi/lo, one
// __syncthreads, 24 k-tiles x 3 mfma (hi*hi + hi*lo + lo*hi), activations
// (lane-local: 4 acc regs = 4 gates of one (row,unit)), h store, grid.sync.
// ---------------------------------------------------------------------------
__global__ __launch_bounds__(NTH, 2) void lstm_main(
    const float* __restrict__ x, const short* __restrict__ Wb_hi,
    const short* __restrict__ Wb_lo, const float* __restrict__ bp,
    float* __restrict__ h0, float* __restrict__ h1)
{
    __shared__ short Alds[2][ROWS][RSTR];   // hi/lo planes, 49,664 B

    const int tid = threadIdx.x;
    const int bid = blockIdx.x;
    const int rt = bid >> 4;                // 16 row tiles
    const int ct = bid & 15;                // 16 col tiles
    const int r0 = rt * ROWS;
    const int n0 = ct * COLS;
    const int wv = tid >> 6;                // wave 0..7
    const int l  = tid & 63;
    const int lane16 = l & 15;
    const int lq = l >> 4;                  // k-group 0..3

    // ---- W fragments to registers (mfma M-side operand), once ----
    // lane's gate-col m = n0 + wv*16 + lane16; k = kt*32 + lq*8 + j
    s16x8 wh[NKT], wl[NKT];
    {
        const size_t colbase = (size_t)(n0 + wv * 16 + lane16) * KTOT;
        #pragma unroll
        for (int kt = 0; kt < NKT; ++kt) {
            wh[kt] = *(const s16x8*)(Wb_hi + colbase + kt * 32 + lq * 8);
            wl[kt] = *(const s16x8*)(Wb_lo + colbase + kt * 32 + lq * 8);
        }
    }

    // bias for this lane's unit: gate-cols n0+wv*16+4*lq+{0..3}
    const float4 bias = *(const float4*)(bp + n0 + wv * 16 + 4 * lq);
    const int unit_g = (n0 >> 2) + wv * 4 + lq;   // global unit this lane owns

    // staging mapping: row = tid>>5 (0..15), 6 float4 per thread
    const int srow = tid >> 5;
    const int sl = tid & 31;

    float creg = 0.f;
    cg::grid_group grid = cg::this_grid();

    for (int t = 0; t < SEQL; ++t) {
        const float* __restrict__ hin  = (t & 1) ? h1 : h0;
        float* __restrict__ hout       = (t & 1) ? h0 : h1;

        // ---- stage A = [x_t | h] rows r0..r0+15 into LDS (bf16 hi/lo) ----
        float4 v[6];
        {
            const float* xrow = x + (size_t)(r0 + srow) * (SEQL * DIN) + (size_t)t * DIN;
            const float* hrow = hin + (size_t)(r0 + srow) * DH - DIN;
            #pragma unroll
            for (int i = 0; i < 6; ++i) {
                int k = 4 * sl + 128 * i;            // uniform branch per i
                v[i] = (i < 2) ? *(const float4*)(xrow + k)
                               : *(const float4*)(hrow + k);
            }
        }
        #pragma unroll
        for (int i = 0; i < 6; ++i) {
            int k = 4 * sl + 128 * i;
            short h0b = bf16_rne(v[i].x), h1b = bf16_rne(v[i].y);
            short h2b = bf16_rne(v[i].z), h3b = bf16_rne(v[i].w);
            s16x4 hi4 = { h0b, h1b, h2b, h3b };
            s16x4 lo4 = { bf16_rne(v[i].x - bf16_to_f32(h0b)),
                          bf16_rne(v[i].y - bf16_to_f32(h1b)),
                          bf16_rne(v[i].z - bf16_to_f32(h2b)),
                          bf16_rne(v[i].w - bf16_to_f32(h3b)) };
            *(s16x4*)(&Alds[0][srow][k]) = hi4;
            *(s16x4*)(&Alds[1][srow][k]) = lo4;
        }
        __syncthreads();

        // ---- 24 k-tiles x 3 mfma; 2 independent acc chains ----
        f32x4 acc0 = {0.f, 0.f, 0.f, 0.f};
        f32x4 acc1 = {0.f, 0.f, 0.f, 0.f};
        {
            const short* arow_hi = &Alds[0][lane16][0];
            const short* arow_lo = &Alds[1][lane16][0];
            #pragma unroll
            for (int kt = 0; kt < NKT; ++kt) {
                s16x8 a_hi = *(const s16x8*)(arow_hi + kt * 32 + lq * 8);
                s16x8 a_lo = *(const s16x8*)(arow_lo + kt * 32 + lq * 8);
                if (kt & 1) {
                    acc1 = __builtin_amdgcn_mfma_f32_16x16x32_bf16(wh[kt], a_hi, acc1, 0, 0, 0);
                    acc1 = __builtin_amdgcn_mfma_f32_16x16x32_bf16(wl[kt], a_hi, acc1, 0, 0, 0);
                    acc1 = __builtin_amdgcn_mfma_f32_16x16x32_bf16(wh[kt], a_lo, acc1, 0, 0, 0);
                } else {
                    acc0 = __builtin_amdgcn_mfma_f32_16x16x32_bf16(wh[kt], a_hi, acc0, 0, 0, 0);
                    acc0 = __builtin_amdgcn_mfma_f32_16x16x32_bf16(wl[kt], a_hi, acc0, 0, 0, 0);
                    acc0 = __builtin_amdgcn_mfma_f32_16x16x32_bf16(wh[kt], a_lo, acc0, 0, 0, 0);
                }
            }
        }
        // lane: batch row = lane16, 4 acc regs = gates g,i,f,o of unit_g
        float zg = acc0.x + acc1.x + bias.x;
        float zi = acc0.y + acc1.y + bias.y;
        float zf = acc0.z + acc1.z + bias.z;
        float zo = acc0.w + acc1.w + bias.w;

        float gv = 1.0f / (1.0f + __expf(-zg));   // sigmoid on g (reference quirk)
        float iv = tanhf(zi);
        float fv = tanhf(zf);
        float ov = tanhf(zo);
        creg = gv * iv + creg * fv;
        hout[(size_t)(r0 + lane16) * DH + unit_g] = tanhf(creg) * ov;

        grid.sync();
    }
}

// ---------------------------------------------------------------------------
// Final projection + softmax, fused. One block per batch row.
// ---------------------------------------------------------------------------
__global__ __launch_bounds__(256) void proj_softmax(
    const float* __restrict__ h, const float* __restrict__ Wph,
    const float* __restrict__ bP, float* __restrict__ out)
{
    __shared__ float red[256];
    const int r = blockIdx.x;
    const int tid = threadIdx.x;
    float a0 = 0.f, a1 = 0.f, a2 = 0.f, a3 = 0.f;
    const float* hr = h + (size_t)r * DH;
    for (int k = 0; k < DH; ++k) {
        float hv = hr[k];
        const float* w = Wph + (size_t)k * NCLS;
        a0 += hv * w[tid];
        a1 += hv * w[tid + 256];
        a2 += hv * w[tid + 512];
        a3 += hv * w[tid + 768];
    }
    a0 += bP[tid]; a1 += bP[tid + 256]; a2 += bP[tid + 512]; a3 += bP[tid + 768];

    float m = fmaxf(fmaxf(a0, a1), fmaxf(a2, a3));
    red[tid] = m; __syncthreads();
    for (int s = 128; s > 0; s >>= 1) {
        if (tid < s) red[tid] = fmaxf(red[tid], red[tid + s]);
        __syncthreads();
    }
    m = red[0];
    __syncthreads();

    float e0 = expf(a0 - m), e1 = expf(a1 - m), e2 = expf(a2 - m), e3 = expf(a3 - m);
    red[tid] = e0 + e1 + e2 + e3; __syncthreads();
    for (int s = 128; s > 0; s >>= 1) {
        if (tid < s) red[tid] += red[tid + s];
        __syncthreads();
    }
    const float inv = 1.0f / red[0];

    float* o = out + (size_t)r * NCLS;
    o[tid]       = e0 * inv;
    o[tid + 256] = e1 * inv;
    o[tid + 512] = e2 * inv;
    o[tid + 768] = e3 * inv;
}

// ---------------------------------------------------------------------------
extern "C" void kernel_launch(void* const* d_in, const int* in_sizes, int n_in,
                              void* d_out, int out_size, void* d_ws, size_t ws_size,
                              hipStream_t stream)
{
    const float* x   = (const float*)d_in[0];
    const float* Wgx = (const float*)d_in[1];
    const float* Wgh = (const float*)d_in[2];
    const float* bg  = (const float*)d_in[3];
    const float* Wix = (const float*)d_in[4];
    const float* Wih = (const float*)d_in[5];
    const float* bi  = (const float*)d_in[6];
    const float* Wfx = (const float*)d_in[7];
    const float* Wfh = (const float*)d_in[8];
    const float* bf  = (const float*)d_in[9];
    const float* Wox = (const float*)d_in[10];
    const float* Woh = (const float*)d_in[11];
    const float* bo  = (const float*)d_in[12];
    const float* Wph = (const float*)d_in[13];
    const float* bP  = (const float*)d_in[14];

    char* ws = (char*)d_ws;
    short* Wb_hi = (short*)ws;                               // [2048][768] bf16
    short* Wb_lo = Wb_hi + (size_t)NG * KTOT;                // [2048][768] bf16
    float* bp    = (float*)(Wb_lo + (size_t)NG * KTOT);      // [2048]
    float* h0    = bp + NG;                                  // [256][512]
    float* h1    = h0 + (size_t)BATCH * DH;                  // [256][512]

    pack_kernel<<<(KTOT * NG + 255) / 256, 256, 0, stream>>>(
        Wgx, Wgh, Wix, Wih, Wfx, Wfh, Wox, Woh, bg, bi, bf, bo,
        Wb_hi, Wb_lo, bp, h0);

    void* args[] = {(void*)&x, (void*)&Wb_hi, (void*)&Wb_lo, (void*)&bp,
                    (void*)&h0, (void*)&h1};
    hipLaunchCooperativeKernel((void*)lstm_main, dim3(256), dim3(NTH), args,
                               0, stream);

    // 512 steps -> final h is in h0
    proj_softmax<<<BATCH, 256, 0, stream>>>(h0, Wph, bP, (float*)d_out);
}

// Round 5
// 8090.141 us; speedup vs baseline: 5.6330x; 2.2191x over previous
//
#include <hip/hip_runtime.h>
#include <hip/hip_bf16.h>

typedef __attribute__((ext_vector_type(4))) float f32x4;
typedef __attribute__((ext_vector_type(8))) short s16x8;   // 8 bf16 (4 VGPR) mfma frag
typedef __attribute__((ext_vector_type(4))) short s16x4;   // 4 bf16 (8B)

#define BATCH 256
#define SEQL  512
#define DIN   256
#define DH    512
#define NG    2048   // 4*DH, gate-interleaved: n = 4*unit + gate (0=g,1=i,2=f,3=o)
#define KTOT  768
#define NKT   24     // k-tiles of 32
#define NCLS  1024
#define NTH   512
#define ROWS  16     // batch rows per block
#define COLS  128    // gate cols per block
#define RSTR  776    // padded A_lds row stride (bf16 elems)

// bf16 RNE from f32, bit-twiddle (finite inputs)
__device__ __forceinline__ short bf16_rne(float a) {
    union { float f; unsigned u; } ua; ua.f = a;
    unsigned r = (ua.u + 0x7FFFu + ((ua.u >> 16) & 1u)) >> 16;
    return (short)r;
}
__device__ __forceinline__ float bf16_to_f32(short b) {
    union { unsigned u; float f; } v; v.u = ((unsigned)(unsigned short)b) << 16;
    return v.f;
}

// ---------------------------------------------------------------------------
// Pack W into hi/lo bf16 planes, n-major k-contiguous: Wb[n][k]. Pack biases.
// Zero packed-h buffers (both parities) and barrier state.
// ---------------------------------------------------------------------------
__global__ void pack_kernel(const float* __restrict__ Wgx, const float* __restrict__ Wgh,
                            const float* __restrict__ Wix, const float* __restrict__ Wih,
                            const float* __restrict__ Wfx, const float* __restrict__ Wfh,
                            const float* __restrict__ Wox, const float* __restrict__ Woh,
                            const float* __restrict__ bg,  const float* __restrict__ bi,
                            const float* __restrict__ bf,  const float* __restrict__ bo,
                            short* __restrict__ Wb_hi, short* __restrict__ Wb_lo,
                            float* __restrict__ bp, unsigned* __restrict__ hp,
                            unsigned* __restrict__ bar)
{
    int idx = blockIdx.x * blockDim.x + threadIdx.x;
    if (idx < KTOT * NG) {
        int n = idx / KTOT;
        int k = idx - n * KTOT;
        int unit = n >> 2;
        int gate = n & 3;
        float v;
        if (k < DIN) {
            const float* src = (gate == 0) ? Wgx : (gate == 1) ? Wix : (gate == 2) ? Wfx : Wox;
            v = src[k * DH + unit];
        } else {
            const float* src = (gate == 0) ? Wgh : (gate == 1) ? Wih : (gate == 2) ? Wfh : Woh;
            v = src[(k - DIN) * DH + unit];
        }
        short hi = bf16_rne(v);
        short lo = bf16_rne(v - bf16_to_f32(hi));
        Wb_hi[idx] = hi;
        Wb_lo[idx] = lo;
    }
    if (idx < NG) {
        int unit = idx >> 2;
        int gate = idx & 3;
        const float* bsrc = (gate == 0) ? bg : (gate == 1) ? bi : (gate == 2) ? bf : bo;
        bp[idx] = bsrc[unit];
    }
    if (idx < 2 * BATCH * DH) hp[idx] = 0u;   // both h parities (packed bf16 pair, 0 == 0.0)
    if (idx < 1024) bar[idx] = 0u;            // barrier counters + flags
}

// ---------------------------------------------------------------------------
// Persistent split-bf16 MFMA LSTM. 256 blocks (16 row-groups x 16 col-tiles)
// x 512 threads. W frags pinned in 192 VGPRs (asm "+v" per step blocks
// rematerialization). h moves as packed bf16 hi/lo u32 via PLAIN cached
// loads/stores; visibility is guaranteed by a per-row-group barrier with
// RELEASE fetch_add on arrive (wbl2: flush dirty L2) and ACQUIRE RMW polls
// on the flag (inv after: refetch h from coherent point). All flag/ctr
// traffic is atomic RMW -> cannot spin on a stale L2 line (wedge-proof).
// ---------------------------------------------------------------------------
__global__ __launch_bounds__(NTH, 2) void lstm_main(
    const float* __restrict__ x, const short* __restrict__ Wb_hi,
    const short* __restrict__ Wb_lo, const float* __restrict__ bp,
    unsigned* __restrict__ hp0, unsigned* __restrict__ hp1,
    unsigned* __restrict__ bar)
{
    __shared__ short Alds[2][ROWS][RSTR];   // hi/lo planes

    const int tid = threadIdx.x;
    const int bid = blockIdx.x;
    const int rt = bid >> 4;                // row-group 0..15
    const int ct = bid & 15;                // col tile 0..15
    const int r0 = rt * ROWS;
    const int n0 = ct * COLS;
    const int wv = tid >> 6;                // wave 0..7
    const int l  = tid & 63;
    const int lane16 = l & 15;
    const int lq = l >> 4;                  // k-group 0..3

    // ---- W fragments to registers, once ----
    s16x8 wh[NKT], wl[NKT];
    {
        const size_t colbase = (size_t)(n0 + wv * 16 + lane16) * KTOT;
        #pragma unroll
        for (int kt = 0; kt < NKT; ++kt) {
            wh[kt] = *(const s16x8*)(Wb_hi + colbase + kt * 32 + lq * 8);
            wl[kt] = *(const s16x8*)(Wb_lo + colbase + kt * 32 + lq * 8);
        }
    }

    const float4 bias = *(const float4*)(bp + n0 + wv * 16 + 4 * lq);
    const int unit_g = (n0 >> 2) + wv * 4 + lq;

    const int srow = tid >> 5;              // staging row 0..15
    const int sl = tid & 31;

    unsigned* ctr  = bar + rt * 32;         // 128B-padded per group
    unsigned* flag = bar + 512 + rt * 32;

    float creg = 0.f;

    // x prologue prefetch (t=0)
    float4 xv0, xv1;
    {
        const float* xr = x + (size_t)(r0 + srow) * (SEQL * DIN);
        xv0 = *(const float4*)(xr + 4 * sl);
        xv1 = *(const float4*)(xr + 4 * sl + 128);
    }

    for (int t = 0; t < SEQL; ++t) {
        // ---- pin W frags in registers (no-op asm; blocks rematerialization) ----
        asm volatile("" : "+v"(wh[0]),"+v"(wh[1]),"+v"(wh[2]),"+v"(wh[3]),"+v"(wh[4]),"+v"(wh[5]),"+v"(wh[6]),"+v"(wh[7]),"+v"(wh[8]),"+v"(wh[9]),"+v"(wh[10]),"+v"(wh[11]));
        asm volatile("" : "+v"(wh[12]),"+v"(wh[13]),"+v"(wh[14]),"+v"(wh[15]),"+v"(wh[16]),"+v"(wh[17]),"+v"(wh[18]),"+v"(wh[19]),"+v"(wh[20]),"+v"(wh[21]),"+v"(wh[22]),"+v"(wh[23]));
        asm volatile("" : "+v"(wl[0]),"+v"(wl[1]),"+v"(wl[2]),"+v"(wl[3]),"+v"(wl[4]),"+v"(wl[5]),"+v"(wl[6]),"+v"(wl[7]),"+v"(wl[8]),"+v"(wl[9]),"+v"(wl[10]),"+v"(wl[11]));
        asm volatile("" : "+v"(wl[12]),"+v"(wl[13]),"+v"(wl[14]),"+v"(wl[15]),"+v"(wl[16]),"+v"(wl[17]),"+v"(wl[18]),"+v"(wl[19]),"+v"(wl[20]),"+v"(wl[21]),"+v"(wl[22]),"+v"(wl[23]));

        const unsigned* __restrict__ hin = (t & 1) ? hp1 : hp0;
        unsigned* __restrict__ hout      = (t & 1) ? hp0 : hp1;

        // ---- h loads: PLAIN cached loads (fresh: acquire-inv at prior barrier) ----
        unsigned long long hvl[8];
        {
            const unsigned* hrow = hin + (size_t)(r0 + srow) * DH + 2 * sl;
            #pragma unroll
            for (int j = 0; j < 8; ++j)
                hvl[j] = *(const unsigned long long*)(hrow + 64 * j);
        }

        // ---- x part -> LDS planes (prefetched regs) ----
        {
            float4 v = xv0; int k0 = 4 * sl;
            #pragma unroll
            for (int i = 0; i < 2; ++i) {
                short h0b = bf16_rne(v.x), h1b = bf16_rne(v.y);
                short h2b = bf16_rne(v.z), h3b = bf16_rne(v.w);
                s16x4 hi4 = { h0b, h1b, h2b, h3b };
                s16x4 lo4 = { bf16_rne(v.x - bf16_to_f32(h0b)),
                              bf16_rne(v.y - bf16_to_f32(h1b)),
                              bf16_rne(v.z - bf16_to_f32(h2b)),
                              bf16_rne(v.w - bf16_to_f32(h3b)) };
                *(s16x4*)(&Alds[0][srow][k0]) = hi4;
                *(s16x4*)(&Alds[1][srow][k0]) = lo4;
                v = xv1; k0 = 4 * sl + 128;
            }
        }

        // ---- h part -> LDS planes (unpack hi/lo pairs with v_perm) ----
        #pragma unroll
        for (int j = 0; j < 8; ++j) {
            unsigned w0 = (unsigned)hvl[j];
            unsigned w1 = (unsigned)(hvl[j] >> 32);
            unsigned hi = __builtin_amdgcn_perm(w1, w0, 0x05040100u);
            unsigned lo = __builtin_amdgcn_perm(w1, w0, 0x07060302u);
            int k0 = DIN + 2 * sl + 64 * j;
            *(unsigned*)(&Alds[0][srow][k0]) = hi;
            *(unsigned*)(&Alds[1][srow][k0]) = lo;
        }
        __syncthreads();

        // ---- 24 k-tiles x 3 mfma; 2 independent acc chains ----
        f32x4 acc0 = {0.f, 0.f, 0.f, 0.f};
        f32x4 acc1 = {0.f, 0.f, 0.f, 0.f};
        {
            const short* arow_hi = &Alds[0][lane16][0];
            const short* arow_lo = &Alds[1][lane16][0];
            #pragma unroll
            for (int kt = 0; kt < NKT; ++kt) {
                s16x8 a_hi = *(const s16x8*)(arow_hi + kt * 32 + lq * 8);
                s16x8 a_lo = *(const s16x8*)(arow_lo + kt * 32 + lq * 8);
                if (kt & 1) {
                    acc1 = __builtin_amdgcn_mfma_f32_16x16x32_bf16(wh[kt], a_hi, acc1, 0, 0, 0);
                    acc1 = __builtin_amdgcn_mfma_f32_16x16x32_bf16(wl[kt], a_hi, acc1, 0, 0, 0);
                    acc1 = __builtin_amdgcn_mfma_f32_16x16x32_bf16(wh[kt], a_lo, acc1, 0, 0, 0);
                } else {
                    acc0 = __builtin_amdgcn_mfma_f32_16x16x32_bf16(wh[kt], a_hi, acc0, 0, 0, 0);
                    acc0 = __builtin_amdgcn_mfma_f32_16x16x32_bf16(wl[kt], a_hi, acc0, 0, 0, 0);
                    acc0 = __builtin_amdgcn_mfma_f32_16x16x32_bf16(wh[kt], a_lo, acc0, 0, 0, 0);
                }
            }
        }

        float zg = acc0.x + acc1.x + bias.x;
        float zi = acc0.y + acc1.y + bias.y;
        float zf = acc0.z + acc1.z + bias.z;
        float zo = acc0.w + acc1.w + bias.w;

        float gv = 1.0f / (1.0f + __expf(-zg));   // sigmoid on g (reference quirk)
        float iv = tanhf(zi);
        float fv = tanhf(zf);
        float ov = tanhf(zo);
        creg = gv * iv + creg * fv;
        float hv = tanhf(creg) * ov;

        // ---- pack h -> u32 (bf16 hi | lo<<16), PLAIN store ----
        {
            short hh = bf16_rne(hv);
            short hlo = bf16_rne(hv - bf16_to_f32(hh));
            unsigned word = (unsigned)(unsigned short)hh |
                            ((unsigned)(unsigned short)hlo << 16);
            hout[(size_t)(r0 + lane16) * DH + unit_g] = word;
        }
        asm volatile("s_waitcnt vmcnt(0)" ::: "memory");   // h stores reached L2
        __syncthreads();                                   // all waves' stores done

        // ---- row-group barrier: arrive (RELEASE: wbl2 flushes dirty h) ----
        if (tid == 0) {
            unsigned old = __hip_atomic_fetch_add(ctr, 1u, __ATOMIC_RELEASE,
                                                  __HIP_MEMORY_SCOPE_AGENT);
            if (old == 16u * (unsigned)(t + 1) - 1u)
                __hip_atomic_fetch_add(flag, 1u, __ATOMIC_RELAXED,
                                       __HIP_MEMORY_SCOPE_AGENT);
        }

        // ---- prefetch x for next step (flies during the spin; regs survive inv) ----
        {
            int tn = (t + 1 < SEQL) ? t + 1 : SEQL - 1;
            const float* xr = x + (size_t)(r0 + srow) * (SEQL * DIN) + (size_t)tn * DIN;
            xv0 = *(const float4*)(xr + 4 * sl);
            xv1 = *(const float4*)(xr + 4 * sl + 128);
        }
        asm volatile("" ::: "memory");   // keep prefetch issued before the spin

        // ---- row-group barrier: wait (ACQUIRE RMW polls -> coherent, + inv) ----
        if (tid == 0) {
            for (;;) {
                unsigned v = __hip_atomic_fetch_add(flag, 0u, __ATOMIC_ACQUIRE,
                                                    __HIP_MEMORY_SCOPE_AGENT);
                if (v >= (unsigned)(t + 1)) break;
                __builtin_amdgcn_s_sleep(2);
            }
        }
        __syncthreads();   // release other waves
    }
}

// ---------------------------------------------------------------------------
// Final projection + softmax, fused. One block per batch row. h is packed
// bf16 hi/lo u32; reconstruct f32 = hi + lo.
// ---------------------------------------------------------------------------
__global__ __launch_bounds__(256) void proj_softmax(
    const unsigned* __restrict__ h, const float* __restrict__ Wph,
    const float* __restrict__ bP, float* __restrict__ out)
{
    __shared__ float red[256];
    const int r = blockIdx.x;
    const int tid = threadIdx.x;
    float a0 = 0.f, a1 = 0.f, a2 = 0.f, a3 = 0.f;
    const unsigned* hr = h + (size_t)r * DH;
    for (int k = 0; k < DH; ++k) {
        unsigned wd = hr[k];
        float hvv = bf16_to_f32((short)(wd & 0xffffu)) + bf16_to_f32((short)(wd >> 16));
        const float* w = Wph + (size_t)k * NCLS;
        a0 += hvv * w[tid];
        a1 += hvv * w[tid + 256];
        a2 += hvv * w[tid + 512];
        a3 += hvv * w[tid + 768];
    }
    a0 += bP[tid]; a1 += bP[tid + 256]; a2 += bP[tid + 512]; a3 += bP[tid + 768];

    float m = fmaxf(fmaxf(a0, a1), fmaxf(a2, a3));
    red[tid] = m; __syncthreads();
    for (int s = 128; s > 0; s >>= 1) {
        if (tid < s) red[tid] = fmaxf(red[tid], red[tid + s]);
        __syncthreads();
    }
    m = red[0];
    __syncthreads();

    float e0 = expf(a0 - m), e1 = expf(a1 - m), e2 = expf(a2 - m), e3 = expf(a3 - m);
    red[tid] = e0 + e1 + e2 + e3; __syncthreads();
    for (int s = 128; s > 0; s >>= 1) {
        if (tid < s) red[tid] += red[tid + s];
        __syncthreads();
    }
    const float inv = 1.0f / red[0];

    float* o = out + (size_t)r * NCLS;
    o[tid]       = e0 * inv;
    o[tid + 256] = e1 * inv;
    o[tid + 512] = e2 * inv;
    o[tid + 768] = e3 * inv;
}

// ---------------------------------------------------------------------------
extern "C" void kernel_launch(void* const* d_in, const int* in_sizes, int n_in,
                              void* d_out, int out_size, void* d_ws, size_t ws_size,
                              hipStream_t stream)
{
    const float* x   = (const float*)d_in[0];
    const float* Wgx = (const float*)d_in[1];
    const float* Wgh = (const float*)d_in[2];
    const float* bg  = (const float*)d_in[3];
    const float* Wix = (const float*)d_in[4];
    const float* Wih = (const float*)d_in[5];
    const float* bi  = (const float*)d_in[6];
    const float* Wfx = (const float*)d_in[7];
    const float* Wfh = (const float*)d_in[8];
    const float* bf  = (const float*)d_in[9];
    const float* Wox = (const float*)d_in[10];
    const float* Woh = (const float*)d_in[11];
    const float* bo  = (const float*)d_in[12];
    const float* Wph = (const float*)d_in[13];
    const float* bP  = (const float*)d_in[14];

    char* ws = (char*)d_ws;
    short* Wb_hi   = (short*)ws;                             // [2048][768] bf16
    short* Wb_lo   = Wb_hi + (size_t)NG * KTOT;              // [2048][768] bf16
    float* bp      = (float*)(Wb_lo + (size_t)NG * KTOT);    // [2048]
    unsigned* hp0  = (unsigned*)(bp + NG);                   // [256][512] packed bf16 pair
    unsigned* hp1  = hp0 + (size_t)BATCH * DH;
    unsigned* bar  = hp1 + (size_t)BATCH * DH;               // 16 ctrs + 16 flags, 128B padded

    pack_kernel<<<(KTOT * NG + 255) / 256, 256, 0, stream>>>(
        Wgx, Wgh, Wix, Wih, Wfx, Wfh, Wox, Woh, bg, bi, bf, bo,
        Wb_hi, Wb_lo, bp, hp0, bar);

    void* args[] = {(void*)&x, (void*)&Wb_hi, (void*)&Wb_lo, (void*)&bp,
                    (void*)&hp0, (void*)&hp1, (void*)&bar};
    hipLaunchCooperativeKernel((void*)lstm_main, dim3(256), dim3(NTH), args,
                               0, stream);

    // 512 steps -> final h is in hp0
    proj_softmax<<<BATCH, 256, 0, stream>>>(hp0, Wph, bP, (float*)d_out);
}

// Round 6
// 2413.056 us; speedup vs baseline: 18.8856x; 3.3527x over previous
//
#include <hip/hip_runtime.h>
#include <hip/hip_bf16.h>

typedef __attribute__((ext_vector_type(4))) float f32x4;
typedef __attribute__((ext_vector_type(8))) short s16x8;   // 8 bf16 (4 VGPR) mfma frag
typedef __attribute__((ext_vector_type(4))) short s16x4;   // 4 bf16 (8B)

#define BATCH 256
#define SEQL  512
#define DIN   256
#define DH    512
#define NG    2048   // 4*DH, gate-interleaved: n = 4*unit + gate (0=g,1=i,2=f,3=o)
#define KTOT  768
#define NKT   24     // k-tiles of 32
#define NCLS  1024
#define NTH   512
#define ROWS  16     // batch rows per block
#define COLS  128    // gate cols per block
#define RSTR  776    // padded A_lds row stride (bf16 elems)

// bf16 RNE from f32, bit-twiddle (finite inputs)
__device__ __forceinline__ short bf16_rne(float a) {
    union { float f; unsigned u; } ua; ua.f = a;
    unsigned r = (ua.u + 0x7FFFu + ((ua.u >> 16) & 1u)) >> 16;
    return (short)r;
}
__device__ __forceinline__ float bf16_to_f32(short b) {
    union { unsigned u; float f; } v; v.u = ((unsigned)(unsigned short)b) << 16;
    return v.f;
}

// ---------------------------------------------------------------------------
// Pack W into hi/lo bf16 planes, n-major k-contiguous: Wb[n][k]. Pack biases.
// Zero packed-h buffers (both parities) and barrier state.
// ---------------------------------------------------------------------------
__global__ void pack_kernel(const float* __restrict__ Wgx, const float* __restrict__ Wgh,
                            const float* __restrict__ Wix, const float* __restrict__ Wih,
                            const float* __restrict__ Wfx, const float* __restrict__ Wfh,
                            const float* __restrict__ Wox, const float* __restrict__ Woh,
                            const float* __restrict__ bg,  const float* __restrict__ bi,
                            const float* __restrict__ bf,  const float* __restrict__ bo,
                            short* __restrict__ Wb_hi, short* __restrict__ Wb_lo,
                            float* __restrict__ bp, unsigned* __restrict__ hp,
                            unsigned* __restrict__ bar)
{
    int idx = blockIdx.x * blockDim.x + threadIdx.x;
    if (idx < KTOT * NG) {
        int n = idx / KTOT;
        int k = idx - n * KTOT;
        int unit = n >> 2;
        int gate = n & 3;
        float v;
        if (k < DIN) {
            const float* src = (gate == 0) ? Wgx : (gate == 1) ? Wix : (gate == 2) ? Wfx : Wox;
            v = src[k * DH + unit];
        } else {
            const float* src = (gate == 0) ? Wgh : (gate == 1) ? Wih : (gate == 2) ? Wfh : Woh;
            v = src[(k - DIN) * DH + unit];
        }
        short hi = bf16_rne(v);
        short lo = bf16_rne(v - bf16_to_f32(hi));
        Wb_hi[idx] = hi;
        Wb_lo[idx] = lo;
    }
    if (idx < NG) {
        int unit = idx >> 2;
        int gate = idx & 3;
        const float* bsrc = (gate == 0) ? bg : (gate == 1) ? bi : (gate == 2) ? bf : bo;
        bp[idx] = bsrc[unit];
    }
    if (idx < 2 * BATCH * DH) hp[idx] = 0u;   // both h parities (packed bf16 pair, 0 == 0.0)
    if (idx < 1024) bar[idx] = 0u;            // barrier counters + flags
}

// ---------------------------------------------------------------------------
// Persistent split-bf16 MFMA LSTM. 256 blocks (16 row-groups x 16 col-tiles)
// x 512 threads. W frags pinned in registers (asm "+v" per step; lives as
// 128 AGPR + 64 VGPR on the unified gfx950 file). NO release/acquire fences
// anywhere (no wbl2/inv L2 walks): h moves as packed bf16 hi/lo u32 via
// RELAXED agent-scope atomic load/store (coherent-point access, L2 state
// untouched -> x stays L2-warm). Barrier: per-row-group (16 blocks),
// monotonic ctr + flag; arrive AND polls are atomic RMWs (must be serviced
// at the coherent point -> stale-L2 infinite spin impossible). Ordering by
// completion: vmcnt(0) drains h stores before arrive; consumer issues h
// loads only after its poll RMW returned flag >= t+1.
// ---------------------------------------------------------------------------
__global__ __launch_bounds__(NTH, 2) void lstm_main(
    const float* __restrict__ x, const short* __restrict__ Wb_hi,
    const short* __restrict__ Wb_lo, const float* __restrict__ bp,
    unsigned* __restrict__ hp0, unsigned* __restrict__ hp1,
    unsigned* __restrict__ bar)
{
    __shared__ short Alds[2][ROWS][RSTR];   // hi/lo planes

    const int tid = threadIdx.x;
    const int bid = blockIdx.x;
    const int rt = bid >> 4;                // row-group 0..15
    const int ct = bid & 15;                // col tile 0..15
    const int r0 = rt * ROWS;
    const int n0 = ct * COLS;
    const int wv = tid >> 6;                // wave 0..7
    const int l  = tid & 63;
    const int lane16 = l & 15;
    const int lq = l >> 4;                  // k-group 0..3

    // ---- W fragments to registers, once ----
    s16x8 wh[NKT], wl[NKT];
    {
        const size_t colbase = (size_t)(n0 + wv * 16 + lane16) * KTOT;
        #pragma unroll
        for (int kt = 0; kt < NKT; ++kt) {
            wh[kt] = *(const s16x8*)(Wb_hi + colbase + kt * 32 + lq * 8);
            wl[kt] = *(const s16x8*)(Wb_lo + colbase + kt * 32 + lq * 8);
        }
    }

    const float4 bias = *(const float4*)(bp + n0 + wv * 16 + 4 * lq);
    const int unit_g = (n0 >> 2) + wv * 4 + lq;

    const int srow = tid >> 5;              // staging row 0..15
    const int sl = tid & 31;

    unsigned* ctr  = bar + rt * 32;         // 128B-padded per group
    unsigned* flag = bar + 512 + rt * 32;

    float creg = 0.f;

    // x prologue prefetch (t=0)
    float4 xv0, xv1;
    {
        const float* xr = x + (size_t)(r0 + srow) * (SEQL * DIN);
        xv0 = *(const float4*)(xr + 4 * sl);
        xv1 = *(const float4*)(xr + 4 * sl + 128);
    }

    for (int t = 0; t < SEQL; ++t) {
        // ---- pin W frags in registers (no-op asm; blocks rematerialization) ----
        asm volatile("" : "+v"(wh[0]),"+v"(wh[1]),"+v"(wh[2]),"+v"(wh[3]),"+v"(wh[4]),"+v"(wh[5]),"+v"(wh[6]),"+v"(wh[7]),"+v"(wh[8]),"+v"(wh[9]),"+v"(wh[10]),"+v"(wh[11]));
        asm volatile("" : "+v"(wh[12]),"+v"(wh[13]),"+v"(wh[14]),"+v"(wh[15]),"+v"(wh[16]),"+v"(wh[17]),"+v"(wh[18]),"+v"(wh[19]),"+v"(wh[20]),"+v"(wh[21]),"+v"(wh[22]),"+v"(wh[23]));
        asm volatile("" : "+v"(wl[0]),"+v"(wl[1]),"+v"(wl[2]),"+v"(wl[3]),"+v"(wl[4]),"+v"(wl[5]),"+v"(wl[6]),"+v"(wl[7]),"+v"(wl[8]),"+v"(wl[9]),"+v"(wl[10]),"+v"(wl[11]));
        asm volatile("" : "+v"(wl[12]),"+v"(wl[13]),"+v"(wl[14]),"+v"(wl[15]),"+v"(wl[16]),"+v"(wl[17]),"+v"(wl[18]),"+v"(wl[19]),"+v"(wl[20]),"+v"(wl[21]),"+v"(wl[22]),"+v"(wl[23]));

        const unsigned* __restrict__ hin = (t & 1) ? hp1 : hp0;
        unsigned* __restrict__ hout      = (t & 1) ? hp0 : hp1;

        // ---- h loads: RELAXED agent-scope atomics (coherent point, no L2 state) ----
        unsigned long long hvl[8];
        {
            const unsigned* hrow = hin + (size_t)(r0 + srow) * DH + 2 * sl;
            #pragma unroll
            for (int j = 0; j < 8; ++j)
                hvl[j] = __hip_atomic_load((const unsigned long long*)(hrow + 64 * j),
                                           __ATOMIC_RELAXED, __HIP_MEMORY_SCOPE_AGENT);
        }

        // ---- x part -> LDS planes (prefetched regs) ----
        {
            float4 v = xv0; int k0 = 4 * sl;
            #pragma unroll
            for (int i = 0; i < 2; ++i) {
                short h0b = bf16_rne(v.x), h1b = bf16_rne(v.y);
                short h2b = bf16_rne(v.z), h3b = bf16_rne(v.w);
                s16x4 hi4 = { h0b, h1b, h2b, h3b };
                s16x4 lo4 = { bf16_rne(v.x - bf16_to_f32(h0b)),
                              bf16_rne(v.y - bf16_to_f32(h1b)),
                              bf16_rne(v.z - bf16_to_f32(h2b)),
                              bf16_rne(v.w - bf16_to_f32(h3b)) };
                *(s16x4*)(&Alds[0][srow][k0]) = hi4;
                *(s16x4*)(&Alds[1][srow][k0]) = lo4;
                v = xv1; k0 = 4 * sl + 128;
            }
        }

        // ---- h part -> LDS planes (unpack hi/lo pairs with v_perm) ----
        #pragma unroll
        for (int j = 0; j < 8; ++j) {
            unsigned w0 = (unsigned)hvl[j];
            unsigned w1 = (unsigned)(hvl[j] >> 32);
            unsigned hi = __builtin_amdgcn_perm(w1, w0, 0x05040100u);
            unsigned lo = __builtin_amdgcn_perm(w1, w0, 0x07060302u);
            int k0 = DIN + 2 * sl + 64 * j;
            *(unsigned*)(&Alds[0][srow][k0]) = hi;
            *(unsigned*)(&Alds[1][srow][k0]) = lo;
        }
        __syncthreads();

        // ---- 24 k-tiles x 3 mfma; 2 independent acc chains ----
        f32x4 acc0 = {0.f, 0.f, 0.f, 0.f};
        f32x4 acc1 = {0.f, 0.f, 0.f, 0.f};
        {
            const short* arow_hi = &Alds[0][lane16][0];
            const short* arow_lo = &Alds[1][lane16][0];
            #pragma unroll
            for (int kt = 0; kt < NKT; ++kt) {
                s16x8 a_hi = *(const s16x8*)(arow_hi + kt * 32 + lq * 8);
                s16x8 a_lo = *(const s16x8*)(arow_lo + kt * 32 + lq * 8);
                if (kt & 1) {
                    acc1 = __builtin_amdgcn_mfma_f32_16x16x32_bf16(wh[kt], a_hi, acc1, 0, 0, 0);
                    acc1 = __builtin_amdgcn_mfma_f32_16x16x32_bf16(wl[kt], a_hi, acc1, 0, 0, 0);
                    acc1 = __builtin_amdgcn_mfma_f32_16x16x32_bf16(wh[kt], a_lo, acc1, 0, 0, 0);
                } else {
                    acc0 = __builtin_amdgcn_mfma_f32_16x16x32_bf16(wh[kt], a_hi, acc0, 0, 0, 0);
                    acc0 = __builtin_amdgcn_mfma_f32_16x16x32_bf16(wl[kt], a_hi, acc0, 0, 0, 0);
                    acc0 = __builtin_amdgcn_mfma_f32_16x16x32_bf16(wh[kt], a_lo, acc0, 0, 0, 0);
                }
            }
        }

        float zg = acc0.x + acc1.x + bias.x;
        float zi = acc0.y + acc1.y + bias.y;
        float zf = acc0.z + acc1.z + bias.z;
        float zo = acc0.w + acc1.w + bias.w;

        float gv = 1.0f / (1.0f + __expf(-zg));   // sigmoid on g (reference quirk)
        float iv = tanhf(zi);
        float fv = tanhf(zf);
        float ov = tanhf(zo);
        creg = gv * iv + creg * fv;
        float hv = tanhf(creg) * ov;

        // ---- pack h -> u32 (bf16 hi | lo<<16), RELAXED agent-scope store ----
        {
            short hh = bf16_rne(hv);
            short hlo = bf16_rne(hv - bf16_to_f32(hh));
            unsigned word = (unsigned)(unsigned short)hh |
                            ((unsigned)(unsigned short)hlo << 16);
            __hip_atomic_store(hout + (size_t)(r0 + lane16) * DH + unit_g, word,
                               __ATOMIC_RELAXED, __HIP_MEMORY_SCOPE_AGENT);
        }
        asm volatile("s_waitcnt vmcnt(0)" ::: "memory");   // h stores at coherent point
        __syncthreads();                                   // all waves' stores done

        // ---- row-group barrier: arrive (RELAXED RMW; no cache walks) ----
        if (tid == 0) {
            unsigned old = __hip_atomic_fetch_add(ctr, 1u, __ATOMIC_RELAXED,
                                                  __HIP_MEMORY_SCOPE_AGENT);
            if (old == 16u * (unsigned)(t + 1) - 1u)
                __hip_atomic_fetch_add(flag, 1u, __ATOMIC_RELAXED,
                                       __HIP_MEMORY_SCOPE_AGENT);
        }

        // ---- prefetch x for next step (flies during the spin) ----
        {
            int tn = (t + 1 < SEQL) ? t + 1 : SEQL - 1;
            const float* xr = x + (size_t)(r0 + srow) * (SEQL * DIN) + (size_t)tn * DIN;
            xv0 = *(const float4*)(xr + 4 * sl);
            xv1 = *(const float4*)(xr + 4 * sl + 128);
        }
        asm volatile("" ::: "memory");   // keep prefetch issued before the spin

        // ---- row-group barrier: wait (RELAXED RMW polls -> coherent point) ----
        if (tid == 0) {
            for (;;) {
                unsigned v = __hip_atomic_fetch_add(flag, 0u, __ATOMIC_RELAXED,
                                                    __HIP_MEMORY_SCOPE_AGENT);
                if (v >= (unsigned)(t + 1)) break;
                __builtin_amdgcn_s_sleep(2);
            }
        }
        asm volatile("" ::: "memory");   // no compiler reorder of next-step loads above this
        __syncthreads();   // release other waves
    }
}

// ---------------------------------------------------------------------------
// Final projection + softmax, fused. One block per batch row. h is packed
// bf16 hi/lo u32; reconstruct f32 = hi + lo.
// ---------------------------------------------------------------------------
__global__ __launch_bounds__(256) void proj_softmax(
    const unsigned* __restrict__ h, const float* __restrict__ Wph,
    const float* __restrict__ bP, float* __restrict__ out)
{
    __shared__ float red[256];
    const int r = blockIdx.x;
    const int tid = threadIdx.x;
    float a0 = 0.f, a1 = 0.f, a2 = 0.f, a3 = 0.f;
    const unsigned* hr = h + (size_t)r * DH;
    for (int k = 0; k < DH; ++k) {
        unsigned wd = hr[k];
        float hvv = bf16_to_f32((short)(wd & 0xffffu)) + bf16_to_f32((short)(wd >> 16));
        const float* w = Wph + (size_t)k * NCLS;
        a0 += hvv * w[tid];
        a1 += hvv * w[tid + 256];
        a2 += hvv * w[tid + 512];
        a3 += hvv * w[tid + 768];
    }
    a0 += bP[tid]; a1 += bP[tid + 256]; a2 += bP[tid + 512]; a3 += bP[tid + 768];

    float m = fmaxf(fmaxf(a0, a1), fmaxf(a2, a3));
    red[tid] = m; __syncthreads();
    for (int s = 128; s > 0; s >>= 1) {
        if (tid < s) red[tid] = fmaxf(red[tid], red[tid + s]);
        __syncthreads();
    }
    m = red[0];
    __syncthreads();

    float e0 = expf(a0 - m), e1 = expf(a1 - m), e2 = expf(a2 - m), e3 = expf(a3 - m);
    red[tid] = e0 + e1 + e2 + e3; __syncthreads();
    for (int s = 128; s > 0; s >>= 1) {
        if (tid < s) red[tid] += red[tid + s];
        __syncthreads();
    }
    const float inv = 1.0f / red[0];

    float* o = out + (size_t)r * NCLS;
    o[tid]       = e0 * inv;
    o[tid + 256] = e1 * inv;
    o[tid + 512] = e2 * inv;
    o[tid + 768] = e3 * inv;
}

// ---------------------------------------------------------------------------
extern "C" void kernel_launch(void* const* d_in, const int* in_sizes, int n_in,
                              void* d_out, int out_size, void* d_ws, size_t ws_size,
                              hipStream_t stream)
{
    const float* x   = (const float*)d_in[0];
    const float* Wgx = (const float*)d_in[1];
    const float* Wgh = (const float*)d_in[2];
    const float* bg  = (const float*)d_in[3];
    const float* Wix = (const float*)d_in[4];
    const float* Wih = (const float*)d_in[5];
    const float* bi  = (const float*)d_in[6];
    const float* Wfx = (const float*)d_in[7];
    const float* Wfh = (const float*)d_in[8];
    const float* bf  = (const float*)d_in[9];
    const float* Wox = (const float*)d_in[10];
    const float* Woh = (const float*)d_in[11];
    const float* bo  = (const float*)d_in[12];
    const float* Wph = (const float*)d_in[13];
    const float* bP  = (const float*)d_in[14];

    char* ws = (char*)d_ws;
    short* Wb_hi   = (short*)ws;                             // [2048][768] bf16
    short* Wb_lo   = Wb_hi + (size_t)NG * KTOT;              // [2048][768] bf16
    float* bp      = (float*)(Wb_lo + (size_t)NG * KTOT);    // [2048]
    unsigned* hp0  = (unsigned*)(bp + NG);                   // [256][512] packed bf16 pair
    unsigned* hp1  = hp0 + (size_t)BATCH * DH;
    unsigned* bar  = hp1 + (size_t)BATCH * DH;               // 16 ctrs + 16 flags, 128B padded

    pack_kernel<<<(KTOT * NG + 255) / 256, 256, 0, stream>>>(
        Wgx, Wgh, Wix, Wih, Wfx, Wfh, Wox, Woh, bg, bi, bf, bo,
        Wb_hi, Wb_lo, bp, hp0, bar);

    void* args[] = {(void*)&x, (void*)&Wb_hi, (void*)&Wb_lo, (void*)&bp,
                    (void*)&hp0, (void*)&hp1, (void*)&bar};
    hipLaunchCooperativeKernel((void*)lstm_main, dim3(256), dim3(NTH), args,
                               0, stream);

    // 512 steps -> final h is in hp0
    proj_softmax<<<BATCH, 256, 0, stream>>>(hp0, Wph, bP, (float*)d_out);
}

// Round 7
// 2118.573 us; speedup vs baseline: 21.5107x; 1.1390x over previous
//
#include <hip/hip_runtime.h>
#include <hip/hip_bf16.h>

typedef __attribute__((ext_vector_type(4))) float f32x4;
typedef __attribute__((ext_vector_type(8))) short s16x8;   // 8 bf16 (4 VGPR) mfma frag
typedef __attribute__((ext_vector_type(4))) short s16x4;   // 4 bf16 (8B)

#define BATCH 256
#define SEQL  512
#define DIN   256
#define DH    512
#define NG    2048   // 4*DH, gate-interleaved: n = 4*unit + gate (0=g,1=i,2=f,3=o)
#define KTOT  768
#define NKT   24     // total k-tiles of 32 (8 x-tiles + 16 h-tiles)
#define NCLS  1024
#define NTH   512
#define ROWS  16     // batch rows per block
#define COLS  128    // gate cols per block
#define XSTR  264    // x-plane row stride (shorts): 132 words == 4 mod 32 -> conflict-free frag reads
#define HSTR  520    // h-plane row stride (shorts): 260 words == 4 mod 32

// bf16 RNE from f32, bit-twiddle (finite inputs)
__device__ __forceinline__ short bf16_rne(float a) {
    union { float f; unsigned u; } ua; ua.f = a;
    unsigned r = (ua.u + 0x7FFFu + ((ua.u >> 16) & 1u)) >> 16;
    return (short)r;
}
__device__ __forceinline__ float bf16_to_f32(short b) {
    union { unsigned u; float f; } v; v.u = ((unsigned)(unsigned short)b) << 16;
    return v.f;
}

// fast activations: v_exp_f32 + v_rcp_f32 (~1ulp each; saturates correctly at +-inf)
__device__ __forceinline__ float fast_sigmoid(float z) {
    return __builtin_amdgcn_rcpf(1.0f + __expf(-z));
}
__device__ __forceinline__ float fast_tanh(float z) {
    return 1.0f - 2.0f * __builtin_amdgcn_rcpf(__expf(2.0f * z) + 1.0f);
}

// ---------------------------------------------------------------------------
// Pack W into hi/lo bf16 planes, n-major k-contiguous: Wb[n][k]. Pack biases.
// Zero packed-h buffers (both parities) and barrier counters.
// ---------------------------------------------------------------------------
__global__ void pack_kernel(const float* __restrict__ Wgx, const float* __restrict__ Wgh,
                            const float* __restrict__ Wix, const float* __restrict__ Wih,
                            const float* __restrict__ Wfx, const float* __restrict__ Wfh,
                            const float* __restrict__ Wox, const float* __restrict__ Woh,
                            const float* __restrict__ bg,  const float* __restrict__ bi,
                            const float* __restrict__ bf,  const float* __restrict__ bo,
                            short* __restrict__ Wb_hi, short* __restrict__ Wb_lo,
                            float* __restrict__ bp, unsigned* __restrict__ hp,
                            unsigned* __restrict__ bar)
{
    int idx = blockIdx.x * blockDim.x + threadIdx.x;
    if (idx < KTOT * NG) {
        int n = idx / KTOT;
        int k = idx - n * KTOT;
        int unit = n >> 2;
        int gate = n & 3;
        float v;
        if (k < DIN) {
            const float* src = (gate == 0) ? Wgx : (gate == 1) ? Wix : (gate == 2) ? Wfx : Wox;
            v = src[k * DH + unit];
        } else {
            const float* src = (gate == 0) ? Wgh : (gate == 1) ? Wih : (gate == 2) ? Wfh : Woh;
            v = src[(k - DIN) * DH + unit];
        }
        short hi = bf16_rne(v);
        short lo = bf16_rne(v - bf16_to_f32(hi));
        Wb_hi[idx] = hi;
        Wb_lo[idx] = lo;
    }
    if (idx < NG) {
        int unit = idx >> 2;
        int gate = idx & 3;
        const float* bsrc = (gate == 0) ? bg : (gate == 1) ? bi : (gate == 2) ? bf : bo;
        bp[idx] = bsrc[unit];
    }
    if (idx < 2 * BATCH * DH) hp[idx] = 0u;   // both h parities (packed bf16 pair, 0 == 0.0)
    if (idx < 1024) bar[idx] = 0u;            // barrier counters
}

// ---------------------------------------------------------------------------
// Persistent split-bf16 MFMA LSTM. 256 blocks (16 row-groups x 16 col-tiles)
// x 512 threads. W frags pinned in registers. Decoupled arrive/wait barrier:
//   per step: stage x -> sync -> x-MFMA (8 kt)      [overlaps flag window]
//             poll ctr >= 16*t -> sync               [h_{t-1} ready]
//             h loads -> stage h -> sync -> h-MFMA (16 kt)
//             fast activations -> store h -> x-prefetch -> vmcnt(0) -> sync
//             tid0: ctr += 1                         [arrive]
// All sync traffic is relaxed agent-scope RMW (coherent-point serviced, no
// L2 wbl2/inv walks). Safety: writes of step t are gated by poll(ctr>=16t),
// which certifies all blocks' reads of the overwritten h parity (reads
// precede each block's step-(t-1) arrive in program order).
// ---------------------------------------------------------------------------
__global__ __launch_bounds__(NTH, 2) void lstm_main(
    const float* __restrict__ x, const short* __restrict__ Wb_hi,
    const short* __restrict__ Wb_lo, const float* __restrict__ bp,
    unsigned* __restrict__ hp0, unsigned* __restrict__ hp1,
    unsigned* __restrict__ bar)
{
    __shared__ short Xlds[2][ROWS][XSTR];   // hi/lo planes, x part (k 0..255)
    __shared__ short Hlds[2][ROWS][HSTR];   // hi/lo planes, h part (k 256..767)

    const int tid = threadIdx.x;
    const int bid = blockIdx.x;
    const int rt = bid >> 4;                // row-group 0..15
    const int ct = bid & 15;                // col tile 0..15
    const int r0 = rt * ROWS;
    const int n0 = ct * COLS;
    const int wv = tid >> 6;                // wave 0..7
    const int l  = tid & 63;
    const int lane16 = l & 15;
    const int lq = l >> 4;                  // k-group 0..3

    // ---- W fragments to registers, once ----
    s16x8 wh[NKT], wl[NKT];
    {
        const size_t colbase = (size_t)(n0 + wv * 16 + lane16) * KTOT;
        #pragma unroll
        for (int kt = 0; kt < NKT; ++kt) {
            wh[kt] = *(const s16x8*)(Wb_hi + colbase + kt * 32 + lq * 8);
            wl[kt] = *(const s16x8*)(Wb_lo + colbase + kt * 32 + lq * 8);
        }
    }

    const float4 bias = *(const float4*)(bp + n0 + wv * 16 + 4 * lq);
    const int unit_g = (n0 >> 2) + wv * 4 + lq;

    const int srow = tid >> 5;              // staging row 0..15
    const int sl = tid & 31;

    unsigned* ctr = bar + rt * 32;          // 128B-padded per row-group

    float creg = 0.f;

    // x prologue prefetch (t=0)
    float4 xv0, xv1;
    {
        const float* xr = x + (size_t)(r0 + srow) * (SEQL * DIN);
        xv0 = *(const float4*)(xr + 4 * sl);
        xv1 = *(const float4*)(xr + 4 * sl + 128);
    }

    for (int t = 0; t < SEQL; ++t) {
        // ---- pin W frags in registers (no-op asm; blocks rematerialization) ----
        asm volatile("" : "+v"(wh[0]),"+v"(wh[1]),"+v"(wh[2]),"+v"(wh[3]),"+v"(wh[4]),"+v"(wh[5]),"+v"(wh[6]),"+v"(wh[7]),"+v"(wh[8]),"+v"(wh[9]),"+v"(wh[10]),"+v"(wh[11]));
        asm volatile("" : "+v"(wh[12]),"+v"(wh[13]),"+v"(wh[14]),"+v"(wh[15]),"+v"(wh[16]),"+v"(wh[17]),"+v"(wh[18]),"+v"(wh[19]),"+v"(wh[20]),"+v"(wh[21]),"+v"(wh[22]),"+v"(wh[23]));
        asm volatile("" : "+v"(wl[0]),"+v"(wl[1]),"+v"(wl[2]),"+v"(wl[3]),"+v"(wl[4]),"+v"(wl[5]),"+v"(wl[6]),"+v"(wl[7]),"+v"(wl[8]),"+v"(wl[9]),"+v"(wl[10]),"+v"(wl[11]));
        asm volatile("" : "+v"(wl[12]),"+v"(wl[13]),"+v"(wl[14]),"+v"(wl[15]),"+v"(wl[16]),"+v"(wl[17]),"+v"(wl[18]),"+v"(wl[19]),"+v"(wl[20]),"+v"(wl[21]),"+v"(wl[22]),"+v"(wl[23]));

        const unsigned* __restrict__ hin = (t & 1) ? hp1 : hp0;
        unsigned* __restrict__ hout      = (t & 1) ? hp0 : hp1;

        // ---- stage x_t (prefetched regs) -> LDS x planes ----
        {
            float4 v = xv0; int k0 = 4 * sl;
            #pragma unroll
            for (int i = 0; i < 2; ++i) {
                short h0b = bf16_rne(v.x), h1b = bf16_rne(v.y);
                short h2b = bf16_rne(v.z), h3b = bf16_rne(v.w);
                s16x4 hi4 = { h0b, h1b, h2b, h3b };
                s16x4 lo4 = { bf16_rne(v.x - bf16_to_f32(h0b)),
                              bf16_rne(v.y - bf16_to_f32(h1b)),
                              bf16_rne(v.z - bf16_to_f32(h2b)),
                              bf16_rne(v.w - bf16_to_f32(h3b)) };
                *(s16x4*)(&Xlds[0][srow][k0]) = hi4;
                *(s16x4*)(&Xlds[1][srow][k0]) = lo4;
                v = xv1; k0 = 4 * sl + 128;
            }
        }
        __syncthreads();   // (a) x staged

        // ---- x-part MFMA: 8 k-tiles x 3 (overlaps other blocks' arrivals) ----
        f32x4 acc0 = {0.f, 0.f, 0.f, 0.f};
        f32x4 acc1 = {0.f, 0.f, 0.f, 0.f};
        {
            const short* ax_hi = &Xlds[0][lane16][lq * 8];
            const short* ax_lo = &Xlds[1][lane16][lq * 8];
            #pragma unroll
            for (int kt = 0; kt < 8; ++kt) {
                s16x8 a_hi = *(const s16x8*)(ax_hi + kt * 32);
                s16x8 a_lo = *(const s16x8*)(ax_lo + kt * 32);
                if (kt & 1) {
                    acc1 = __builtin_amdgcn_mfma_f32_16x16x32_bf16(wh[kt], a_hi, acc1, 0, 0, 0);
                    acc1 = __builtin_amdgcn_mfma_f32_16x16x32_bf16(wl[kt], a_hi, acc1, 0, 0, 0);
                    acc1 = __builtin_amdgcn_mfma_f32_16x16x32_bf16(wh[kt], a_lo, acc1, 0, 0, 0);
                } else {
                    acc0 = __builtin_amdgcn_mfma_f32_16x16x32_bf16(wh[kt], a_hi, acc0, 0, 0, 0);
                    acc0 = __builtin_amdgcn_mfma_f32_16x16x32_bf16(wl[kt], a_hi, acc0, 0, 0, 0);
                    acc0 = __builtin_amdgcn_mfma_f32_16x16x32_bf16(wh[kt], a_lo, acc0, 0, 0, 0);
                }
            }
        }

        // ---- wait: h_{t-1} ready (ctr >= 16*t; RMW poll -> coherent point) ----
        if (tid == 0) {
            const unsigned need = 16u * (unsigned)t;
            for (;;) {
                unsigned v = __hip_atomic_fetch_add(ctr, 0u, __ATOMIC_RELAXED,
                                                    __HIP_MEMORY_SCOPE_AGENT);
                if (v >= need) break;
                __builtin_amdgcn_s_sleep(1);
            }
        }
        __syncthreads();   // release: h data visible at coherent point

        // ---- h loads (relaxed agent atomics, L2-bypassing) ----
        unsigned long long hvl[8];
        {
            const unsigned* hrow = hin + (size_t)(r0 + srow) * DH + 2 * sl;
            #pragma unroll
            for (int j = 0; j < 8; ++j)
                hvl[j] = __hip_atomic_load((const unsigned long long*)(hrow + 64 * j),
                                           __ATOMIC_RELAXED, __HIP_MEMORY_SCOPE_AGENT);
        }
        // ---- h -> LDS planes (unpack hi/lo pairs with v_perm) ----
        #pragma unroll
        for (int j = 0; j < 8; ++j) {
            unsigned w0 = (unsigned)hvl[j];
            unsigned w1 = (unsigned)(hvl[j] >> 32);
            unsigned hi = __builtin_amdgcn_perm(w1, w0, 0x05040100u);
            unsigned lo = __builtin_amdgcn_perm(w1, w0, 0x07060302u);
            int k0 = 2 * sl + 64 * j;
            *(unsigned*)(&Hlds[0][srow][k0]) = hi;
            *(unsigned*)(&Hlds[1][srow][k0]) = lo;
        }
        __syncthreads();   // (b) h staged

        // ---- h-part MFMA: 16 k-tiles x 3 ----
        {
            const short* ah_hi = &Hlds[0][lane16][lq * 8];
            const short* ah_lo = &Hlds[1][lane16][lq * 8];
            #pragma unroll
            for (int kt = 8; kt < NKT; ++kt) {
                const int ko = (kt - 8) * 32;
                s16x8 a_hi = *(const s16x8*)(ah_hi + ko);
                s16x8 a_lo = *(const s16x8*)(ah_lo + ko);
                if (kt & 1) {
                    acc1 = __builtin_amdgcn_mfma_f32_16x16x32_bf16(wh[kt], a_hi, acc1, 0, 0, 0);
                    acc1 = __builtin_amdgcn_mfma_f32_16x16x32_bf16(wl[kt], a_hi, acc1, 0, 0, 0);
                    acc1 = __builtin_amdgcn_mfma_f32_16x16x32_bf16(wh[kt], a_lo, acc1, 0, 0, 0);
                } else {
                    acc0 = __builtin_amdgcn_mfma_f32_16x16x32_bf16(wh[kt], a_hi, acc0, 0, 0, 0);
                    acc0 = __builtin_amdgcn_mfma_f32_16x16x32_bf16(wl[kt], a_hi, acc0, 0, 0, 0);
                    acc0 = __builtin_amdgcn_mfma_f32_16x16x32_bf16(wh[kt], a_lo, acc0, 0, 0, 0);
                }
            }
        }

        float zg = acc0.x + acc1.x + bias.x;
        float zi = acc0.y + acc1.y + bias.y;
        float zf = acc0.z + acc1.z + bias.z;
        float zo = acc0.w + acc1.w + bias.w;

        float gv = fast_sigmoid(zg);   // sigmoid on g (reference quirk)
        float iv = fast_tanh(zi);
        float fv = fast_tanh(zf);
        float ov = fast_tanh(zo);
        creg = gv * iv + creg * fv;
        float hv = fast_tanh(creg) * ov;

        // ---- pack h -> u32 (bf16 hi | lo<<16), relaxed agent store ----
        {
            short hh = bf16_rne(hv);
            short hlo = bf16_rne(hv - bf16_to_f32(hh));
            unsigned word = (unsigned)(unsigned short)hh |
                            ((unsigned)(unsigned short)hlo << 16);
            __hip_atomic_store(hout + (size_t)(r0 + lane16) * DH + unit_g, word,
                               __ATOMIC_RELAXED, __HIP_MEMORY_SCOPE_AGENT);
        }

        // ---- prefetch x for next step (drains together with the h stores) ----
        {
            int tn = (t + 1 < SEQL) ? t + 1 : SEQL - 1;
            const float* xr = x + (size_t)(r0 + srow) * (SEQL * DIN) + (size_t)tn * DIN;
            xv0 = *(const float4*)(xr + 4 * sl);
            xv1 = *(const float4*)(xr + 4 * sl + 128);
        }

        asm volatile("s_waitcnt vmcnt(0)" ::: "memory");   // h stores at coherent point
        __syncthreads();                                   // (c) all waves drained
        // ---- arrive ----
        if (tid == 0)
            __hip_atomic_fetch_add(ctr, 1u, __ATOMIC_RELAXED, __HIP_MEMORY_SCOPE_AGENT);
    }
}

// ---------------------------------------------------------------------------
// Final projection + softmax, fused. One block per batch row. h is packed
// bf16 hi/lo u32; reconstruct f32 = hi + lo.
// ---------------------------------------------------------------------------
__global__ __launch_bounds__(256) void proj_softmax(
    const unsigned* __restrict__ h, const float* __restrict__ Wph,
    const float* __restrict__ bP, float* __restrict__ out)
{
    __shared__ float red[256];
    const int r = blockIdx.x;
    const int tid = threadIdx.x;
    float a0 = 0.f, a1 = 0.f, a2 = 0.f, a3 = 0.f;
    const unsigned* hr = h + (size_t)r * DH;
    for (int k = 0; k < DH; ++k) {
        unsigned wd = hr[k];
        float hvv = bf16_to_f32((short)(wd & 0xffffu)) + bf16_to_f32((short)(wd >> 16));
        const float* w = Wph + (size_t)k * NCLS;
        a0 += hvv * w[tid];
        a1 += hvv * w[tid + 256];
        a2 += hvv * w[tid + 512];
        a3 += hvv * w[tid + 768];
    }
    a0 += bP[tid]; a1 += bP[tid + 256]; a2 += bP[tid + 512]; a3 += bP[tid + 768];

    float m = fmaxf(fmaxf(a0, a1), fmaxf(a2, a3));
    red[tid] = m; __syncthreads();
    for (int s = 128; s > 0; s >>= 1) {
        if (tid < s) red[tid] = fmaxf(red[tid], red[tid + s]);
        __syncthreads();
    }
    m = red[0];
    __syncthreads();

    float e0 = expf(a0 - m), e1 = expf(a1 - m), e2 = expf(a2 - m), e3 = expf(a3 - m);
    red[tid] = e0 + e1 + e2 + e3; __syncthreads();
    for (int s = 128; s > 0; s >>= 1) {
        if (tid < s) red[tid] += red[tid + s];
        __syncthreads();
    }
    const float inv = 1.0f / red[0];

    float* o = out + (size_t)r * NCLS;
    o[tid]       = e0 * inv;
    o[tid + 256] = e1 * inv;
    o[tid + 512] = e2 * inv;
    o[tid + 768] = e3 * inv;
}

// ---------------------------------------------------------------------------
extern "C" void kernel_launch(void* const* d_in, const int* in_sizes, int n_in,
                              void* d_out, int out_size, void* d_ws, size_t ws_size,
                              hipStream_t stream)
{
    const float* x   = (const float*)d_in[0];
    const float* Wgx = (const float*)d_in[1];
    const float* Wgh = (const float*)d_in[2];
    const float* bg  = (const float*)d_in[3];
    const float* Wix = (const float*)d_in[4];
    const float* Wih = (const float*)d_in[5];
    const float* bi  = (const float*)d_in[6];
    const float* Wfx = (const float*)d_in[7];
    const float* Wfh = (const float*)d_in[8];
    const float* bf  = (const float*)d_in[9];
    const float* Wox = (const float*)d_in[10];
    const float* Woh = (const float*)d_in[11];
    const float* bo  = (const float*)d_in[12];
    const float* Wph = (const float*)d_in[13];
    const float* bP  = (const float*)d_in[14];

    char* ws = (char*)d_ws;
    short* Wb_hi   = (short*)ws;                             // [2048][768] bf16
    short* Wb_lo   = Wb_hi + (size_t)NG * KTOT;              // [2048][768] bf16
    float* bp      = (float*)(Wb_lo + (size_t)NG * KTOT);    // [2048]
    unsigned* hp0  = (unsigned*)(bp + NG);                   // [256][512] packed bf16 pair
    unsigned* hp1  = hp0 + (size_t)BATCH * DH;
    unsigned* bar  = hp1 + (size_t)BATCH * DH;               // 16 ctrs, 128B padded

    pack_kernel<<<(KTOT * NG + 255) / 256, 256, 0, stream>>>(
        Wgx, Wgh, Wix, Wih, Wfx, Wfh, Wox, Woh, bg, bi, bf, bo,
        Wb_hi, Wb_lo, bp, hp0, bar);

    void* args[] = {(void*)&x, (void*)&Wb_hi, (void*)&Wb_lo, (void*)&bp,
                    (void*)&hp0, (void*)&hp1, (void*)&bar};
    hipLaunchCooperativeKernel((void*)lstm_main, dim3(256), dim3(NTH), args,
                               0, stream);

    // 512 steps -> final h is in hp0
    proj_softmax<<<BATCH, 256, 0, stream>>>(hp0, Wph, bP, (float*)d_out);
}

// Round 8
// 1865.101 us; speedup vs baseline: 24.4341x; 1.1359x over previous
//
#include <hip/hip_runtime.h>
#include <hip/hip_bf16.h>

typedef __attribute__((ext_vector_type(4))) float f32x4;
typedef __attribute__((ext_vector_type(8))) short s16x8;   // 8 bf16 (4 VGPR) mfma frag
typedef __attribute__((ext_vector_type(4))) short s16x4;   // 4 bf16 (8B)

#define BATCH 256
#define SEQL  512
#define DIN   256
#define DH    512
#define NG    2048   // 4*DH, gate-interleaved: n = 4*unit + gate (0=g,1=i,2=f,3=o)
#define KTOT  768
#define NKT   24     // total k-tiles of 32 (8 x-tiles + 16 h-tiles)
#define NCLS  1024
#define NTH   512
#define ROWS  16     // batch rows per block
#define COLS  128    // gate cols per block
#define XSTR  264    // x-plane row stride (shorts): 132 words == 4 mod 32 -> conflict-free frag reads
#define HSTR  520    // h-plane row stride (shorts): 260 words == 4 mod 32

// bf16 RNE from f32, bit-twiddle (finite inputs)
__device__ __forceinline__ short bf16_rne(float a) {
    union { float f; unsigned u; } ua; ua.f = a;
    unsigned r = (ua.u + 0x7FFFu + ((ua.u >> 16) & 1u)) >> 16;
    return (short)r;
}
__device__ __forceinline__ float bf16_to_f32(short b) {
    union { unsigned u; float f; } v; v.u = ((unsigned)(unsigned short)b) << 16;
    return v.f;
}

// fast activations: v_exp_f32 + v_rcp_f32 (~1ulp each; saturates correctly at +-inf)
__device__ __forceinline__ float fast_sigmoid(float z) {
    return __builtin_amdgcn_rcpf(1.0f + __expf(-z));
}
__device__ __forceinline__ float fast_tanh(float z) {
    return 1.0f - 2.0f * __builtin_amdgcn_rcpf(__expf(2.0f * z) + 1.0f);
}

// ---------------------------------------------------------------------------
// Pack W into hi/lo bf16 planes, n-major k-contiguous: Wb[n][k]. Pack biases.
// Zero packed-h buffers (both parities) and barrier/init state.
// ---------------------------------------------------------------------------
__global__ void pack_kernel(const float* __restrict__ Wgx, const float* __restrict__ Wgh,
                            const float* __restrict__ Wix, const float* __restrict__ Wih,
                            const float* __restrict__ Wfx, const float* __restrict__ Wfh,
                            const float* __restrict__ Wox, const float* __restrict__ Woh,
                            const float* __restrict__ bg,  const float* __restrict__ bi,
                            const float* __restrict__ bf,  const float* __restrict__ bo,
                            short* __restrict__ Wb_hi, short* __restrict__ Wb_lo,
                            float* __restrict__ bp, unsigned* __restrict__ hp,
                            unsigned* __restrict__ bar)
{
    int idx = blockIdx.x * blockDim.x + threadIdx.x;
    if (idx < KTOT * NG) {
        int n = idx / KTOT;
        int k = idx - n * KTOT;
        int unit = n >> 2;
        int gate = n & 3;
        float v;
        if (k < DIN) {
            const float* src = (gate == 0) ? Wgx : (gate == 1) ? Wix : (gate == 2) ? Wfx : Wox;
            v = src[k * DH + unit];
        } else {
            const float* src = (gate == 0) ? Wgh : (gate == 1) ? Wih : (gate == 2) ? Wfh : Woh;
            v = src[(k - DIN) * DH + unit];
        }
        short hi = bf16_rne(v);
        short lo = bf16_rne(v - bf16_to_f32(hi));
        Wb_hi[idx] = hi;
        Wb_lo[idx] = lo;
    }
    if (idx < NG) {
        int unit = idx >> 2;
        int gate = idx & 3;
        const float* bsrc = (gate == 0) ? bg : (gate == 1) ? bi : (gate == 2) ? bf : bo;
        bp[idx] = bsrc[unit];
    }
    if (idx < 2 * BATCH * DH) hp[idx] = 0u;   // both h parities (packed bf16 pair, 0 == 0.0)
    if (idx < 1024) bar[idx] = 0u;            // barrier ctrs + xcd table + init ctr
    // kernel-end implicit L2 writeback publishes all of this to the coherent point
}

// ---------------------------------------------------------------------------
// Persistent split-bf16 MFMA LSTM. 256 blocks x 512 threads.
// NEW group mapping: rt = bid&15, ct = bid>>4 -> a row-group's 16 blocks are
// bids {rt+16k} == rt (mod 8) -> SAME XCD under round-robin dispatch. Runtime
// verified via HW_REG_XCC_ID exchange + one-shot init barrier; matching
// groups use XCD-LOCAL L2 synchronization:
//   h-store: plain store (lands in XCD L2)     h-load: global_load sc0 (L1-bypass, L2-served)
//   arrive/poll: workgroup-scope fetch_add (global_atomic w/o sc1 -> local L2 RMW)
// Non-matching groups fall back to the proven agent-scope (L3) path. Both
// paths compute identical values -> deterministic output.
// Step schedule (unchanged from r7): stage x -> sync -> x-MFMA (8kt) ->
// poll(ctr>=16t) -> sync -> h-load/stage -> sync -> h-MFMA (16kt) -> act ->
// h-store -> x-prefetch -> vmcnt(0) -> sync -> arrive.
// ---------------------------------------------------------------------------
__global__ __launch_bounds__(NTH, 2) void lstm_main(
    const float* __restrict__ x, const short* __restrict__ Wb_hi,
    const short* __restrict__ Wb_lo, const float* __restrict__ bp,
    unsigned* __restrict__ hp0, unsigned* __restrict__ hp1,
    unsigned* __restrict__ bar)
{
    __shared__ short Xlds[2][ROWS][XSTR];   // hi/lo planes, x part (k 0..255)
    __shared__ short Hlds[2][ROWS][HSTR];   // hi/lo planes, h part (k 256..767)
    __shared__ unsigned mode_sh;

    const int tid = threadIdx.x;
    const int bid = blockIdx.x;
    const int rt = bid & 15;                // row-group 0..15  (XCD-local mapping)
    const int ct = bid >> 4;                // col tile 0..15
    const int r0 = rt * ROWS;
    const int n0 = ct * COLS;
    const int wv = tid >> 6;                // wave 0..7
    const int l  = tid & 63;
    const int lane16 = l & 15;
    const int lq = l >> 4;                  // k-group 0..3

    // ---- init: publish XCC_ID, grid barrier, per-group locality verdict ----
    if (tid == 0) {
        unsigned xcc;
        asm volatile("s_getreg_b32 %0, hwreg(HW_REG_XCC_ID)" : "=s"(xcc));
        __hip_atomic_store(bar + 640 + bid, xcc, __ATOMIC_RELAXED, __HIP_MEMORY_SCOPE_AGENT);
        asm volatile("s_waitcnt vmcnt(0)" ::: "memory");
        __hip_atomic_fetch_add(bar + 896, 1u, __ATOMIC_RELAXED, __HIP_MEMORY_SCOPE_AGENT);
        for (;;) {
            unsigned v = __hip_atomic_fetch_add(bar + 896, 0u, __ATOMIC_RELAXED,
                                                __HIP_MEMORY_SCOPE_AGENT);
            if (v >= 256u) break;
            __builtin_amdgcn_s_sleep(4);
        }
        unsigned ok = 1;
        for (int k2 = 0; k2 < 16; ++k2) {
            unsigned other = __hip_atomic_load(bar + 640 + rt + 16 * k2,
                                               __ATOMIC_RELAXED, __HIP_MEMORY_SCOPE_AGENT);
            ok &= (other == xcc) ? 1u : 0u;
        }
        mode_sh = ok;
    }
    __syncthreads();
    const bool local_mode = (mode_sh != 0);

    // ---- W fragments to registers, once ----
    s16x8 wh[NKT], wl[NKT];
    {
        const size_t colbase = (size_t)(n0 + wv * 16 + lane16) * KTOT;
        #pragma unroll
        for (int kt = 0; kt < NKT; ++kt) {
            wh[kt] = *(const s16x8*)(Wb_hi + colbase + kt * 32 + lq * 8);
            wl[kt] = *(const s16x8*)(Wb_lo + colbase + kt * 32 + lq * 8);
        }
    }

    const float4 bias = *(const float4*)(bp + n0 + wv * 16 + 4 * lq);
    const int unit_g = (n0 >> 2) + wv * 4 + lq;

    const int srow = tid >> 5;              // staging row 0..15
    const int sl = tid & 31;

    unsigned* ctr = bar + rt * 32;          // 128B-padded per row-group

    float creg = 0.f;

    // x prologue prefetch (t=0)
    float4 xv0, xv1;
    {
        const float* xr = x + (size_t)(r0 + srow) * (SEQL * DIN);
        xv0 = *(const float4*)(xr + 4 * sl);
        xv1 = *(const float4*)(xr + 4 * sl + 128);
    }

    for (int t = 0; t < SEQL; ++t) {
        // ---- pin W frags in registers (no-op asm; blocks rematerialization) ----
        asm volatile("" : "+v"(wh[0]),"+v"(wh[1]),"+v"(wh[2]),"+v"(wh[3]),"+v"(wh[4]),"+v"(wh[5]),"+v"(wh[6]),"+v"(wh[7]),"+v"(wh[8]),"+v"(wh[9]),"+v"(wh[10]),"+v"(wh[11]));
        asm volatile("" : "+v"(wh[12]),"+v"(wh[13]),"+v"(wh[14]),"+v"(wh[15]),"+v"(wh[16]),"+v"(wh[17]),"+v"(wh[18]),"+v"(wh[19]),"+v"(wh[20]),"+v"(wh[21]),"+v"(wh[22]),"+v"(wh[23]));
        asm volatile("" : "+v"(wl[0]),"+v"(wl[1]),"+v"(wl[2]),"+v"(wl[3]),"+v"(wl[4]),"+v"(wl[5]),"+v"(wl[6]),"+v"(wl[7]),"+v"(wl[8]),"+v"(wl[9]),"+v"(wl[10]),"+v"(wl[11]));
        asm volatile("" : "+v"(wl[12]),"+v"(wl[13]),"+v"(wl[14]),"+v"(wl[15]),"+v"(wl[16]),"+v"(wl[17]),"+v"(wl[18]),"+v"(wl[19]),"+v"(wl[20]),"+v"(wl[21]),"+v"(wl[22]),"+v"(wl[23]));

        const unsigned* __restrict__ hin = (t & 1) ? hp1 : hp0;
        unsigned* __restrict__ hout      = (t & 1) ? hp0 : hp1;

        // ---- stage x_t (prefetched regs) -> LDS x planes ----
        {
            float4 v = xv0; int k0 = 4 * sl;
            #pragma unroll
            for (int i = 0; i < 2; ++i) {
                short h0b = bf16_rne(v.x), h1b = bf16_rne(v.y);
                short h2b = bf16_rne(v.z), h3b = bf16_rne(v.w);
                s16x4 hi4 = { h0b, h1b, h2b, h3b };
                s16x4 lo4 = { bf16_rne(v.x - bf16_to_f32(h0b)),
                              bf16_rne(v.y - bf16_to_f32(h1b)),
                              bf16_rne(v.z - bf16_to_f32(h2b)),
                              bf16_rne(v.w - bf16_to_f32(h3b)) };
                *(s16x4*)(&Xlds[0][srow][k0]) = hi4;
                *(s16x4*)(&Xlds[1][srow][k0]) = lo4;
                v = xv1; k0 = 4 * sl + 128;
            }
        }
        __syncthreads();   // (a) x staged

        // ---- x-part MFMA: 8 k-tiles x 3 (overlaps other blocks' arrivals) ----
        f32x4 acc0 = {0.f, 0.f, 0.f, 0.f};
        f32x4 acc1 = {0.f, 0.f, 0.f, 0.f};
        {
            const short* ax_hi = &Xlds[0][lane16][lq * 8];
            const short* ax_lo = &Xlds[1][lane16][lq * 8];
            #pragma unroll
            for (int kt = 0; kt < 8; ++kt) {
                s16x8 a_hi = *(const s16x8*)(ax_hi + kt * 32);
                s16x8 a_lo = *(const s16x8*)(ax_lo + kt * 32);
                if (kt & 1) {
                    acc1 = __builtin_amdgcn_mfma_f32_16x16x32_bf16(wh[kt], a_hi, acc1, 0, 0, 0);
                    acc1 = __builtin_amdgcn_mfma_f32_16x16x32_bf16(wl[kt], a_hi, acc1, 0, 0, 0);
                    acc1 = __builtin_amdgcn_mfma_f32_16x16x32_bf16(wh[kt], a_lo, acc1, 0, 0, 0);
                } else {
                    acc0 = __builtin_amdgcn_mfma_f32_16x16x32_bf16(wh[kt], a_hi, acc0, 0, 0, 0);
                    acc0 = __builtin_amdgcn_mfma_f32_16x16x32_bf16(wl[kt], a_hi, acc0, 0, 0, 0);
                    acc0 = __builtin_amdgcn_mfma_f32_16x16x32_bf16(wh[kt], a_lo, acc0, 0, 0, 0);
                }
            }
        }

        // ---- wait: h_{t-1} ready (ctr >= 16*t) ----
        if (tid == 0) {
            const unsigned need = 16u * (unsigned)t;
            if (local_mode) {
                for (;;) {
                    unsigned v = __hip_atomic_fetch_add(ctr, 0u, __ATOMIC_RELAXED,
                                                        __HIP_MEMORY_SCOPE_WORKGROUP);
                    if (v >= need) break;
                    __builtin_amdgcn_s_sleep(1);
                }
            } else {
                for (;;) {
                    unsigned v = __hip_atomic_fetch_add(ctr, 0u, __ATOMIC_RELAXED,
                                                        __HIP_MEMORY_SCOPE_AGENT);
                    if (v >= need) break;
                    __builtin_amdgcn_s_sleep(1);
                }
            }
        }
        __syncthreads();   // release: h data visible at this group's coherence point

        // ---- h loads ----
        unsigned long long hvl[8];
        {
            const unsigned* hrow = hin + (size_t)(r0 + srow) * DH + 2 * sl;
            if (local_mode) {
                const unsigned long long* p = (const unsigned long long*)hrow;
                #pragma unroll
                for (int j = 0; j < 8; ++j)
                    asm volatile("global_load_dwordx2 %0, %1, off sc0"
                                 : "=v"(hvl[j]) : "v"(p + 32 * j));
                asm volatile("s_waitcnt vmcnt(0)" ::: "memory");
                __builtin_amdgcn_sched_barrier(0);
            } else {
                #pragma unroll
                for (int j = 0; j < 8; ++j)
                    hvl[j] = __hip_atomic_load((const unsigned long long*)(hrow + 64 * j),
                                               __ATOMIC_RELAXED, __HIP_MEMORY_SCOPE_AGENT);
            }
        }
        // ---- h -> LDS planes (unpack hi/lo pairs with v_perm) ----
        #pragma unroll
        for (int j = 0; j < 8; ++j) {
            unsigned w0 = (unsigned)hvl[j];
            unsigned w1 = (unsigned)(hvl[j] >> 32);
            unsigned hi = __builtin_amdgcn_perm(w1, w0, 0x05040100u);
            unsigned lo = __builtin_amdgcn_perm(w1, w0, 0x07060302u);
            int k0 = 2 * sl + 64 * j;
            *(unsigned*)(&Hlds[0][srow][k0]) = hi;
            *(unsigned*)(&Hlds[1][srow][k0]) = lo;
        }
        __syncthreads();   // (b) h staged

        // ---- h-part MFMA: 16 k-tiles x 3 ----
        {
            const short* ah_hi = &Hlds[0][lane16][lq * 8];
            const short* ah_lo = &Hlds[1][lane16][lq * 8];
            #pragma unroll
            for (int kt = 8; kt < NKT; ++kt) {
                const int ko = (kt - 8) * 32;
                s16x8 a_hi = *(const s16x8*)(ah_hi + ko);
                s16x8 a_lo = *(const s16x8*)(ah_lo + ko);
                if (kt & 1) {
                    acc1 = __builtin_amdgcn_mfma_f32_16x16x32_bf16(wh[kt], a_hi, acc1, 0, 0, 0);
                    acc1 = __builtin_amdgcn_mfma_f32_16x16x32_bf16(wl[kt], a_hi, acc1, 0, 0, 0);
                    acc1 = __builtin_amdgcn_mfma_f32_16x16x32_bf16(wh[kt], a_lo, acc1, 0, 0, 0);
                } else {
                    acc0 = __builtin_amdgcn_mfma_f32_16x16x32_bf16(wh[kt], a_hi, acc0, 0, 0, 0);
                    acc0 = __builtin_amdgcn_mfma_f32_16x16x32_bf16(wl[kt], a_hi, acc0, 0, 0, 0);
                    acc0 = __builtin_amdgcn_mfma_f32_16x16x32_bf16(wh[kt], a_lo, acc0, 0, 0, 0);
                }
            }
        }

        float zg = acc0.x + acc1.x + bias.x;
        float zi = acc0.y + acc1.y + bias.y;
        float zf = acc0.z + acc1.z + bias.z;
        float zo = acc0.w + acc1.w + bias.w;

        float gv = fast_sigmoid(zg);   // sigmoid on g (reference quirk)
        float iv = fast_tanh(zi);
        float fv = fast_tanh(zf);
        float ov = fast_tanh(zo);
        creg = gv * iv + creg * fv;
        float hv = fast_tanh(creg) * ov;

        // ---- pack h -> u32 (bf16 hi | lo<<16) and store ----
        {
            short hh = bf16_rne(hv);
            short hlo = bf16_rne(hv - bf16_to_f32(hh));
            unsigned word = (unsigned)(unsigned short)hh |
                            ((unsigned)(unsigned short)hlo << 16);
            unsigned* dst = hout + (size_t)(r0 + lane16) * DH + unit_g;
            if (local_mode) {
                *dst = word;                               // plain store -> XCD L2
            } else {
                __hip_atomic_store(dst, word, __ATOMIC_RELAXED, __HIP_MEMORY_SCOPE_AGENT);
            }
        }

        // ---- prefetch x for next step (drains together with the h stores) ----
        {
            int tn = (t + 1 < SEQL) ? t + 1 : SEQL - 1;
            const float* xr = x + (size_t)(r0 + srow) * (SEQL * DIN) + (size_t)tn * DIN;
            xv0 = *(const float4*)(xr + 4 * sl);
            xv1 = *(const float4*)(xr + 4 * sl + 128);
        }

        asm volatile("s_waitcnt vmcnt(0)" ::: "memory");   // h stores complete at group coherence point
        __syncthreads();                                   // (c) all waves drained
        // ---- arrive ----
        if (tid == 0) {
            if (local_mode)
                __hip_atomic_fetch_add(ctr, 1u, __ATOMIC_RELAXED, __HIP_MEMORY_SCOPE_WORKGROUP);
            else
                __hip_atomic_fetch_add(ctr, 1u, __ATOMIC_RELAXED, __HIP_MEMORY_SCOPE_AGENT);
        }
    }
}

// ---------------------------------------------------------------------------
// Final projection + softmax, fused. One block per batch row. h is packed
// bf16 hi/lo u32; reconstruct f32 = hi + lo. (Kernel-boundary L2 writeback
// publishes local-mode h to this kernel.)
// ---------------------------------------------------------------------------
__global__ __launch_bounds__(256) void proj_softmax(
    const unsigned* __restrict__ h, const float* __restrict__ Wph,
    const float* __restrict__ bP, float* __restrict__ out)
{
    __shared__ float red[256];
    const int r = blockIdx.x;
    const int tid = threadIdx.x;
    float a0 = 0.f, a1 = 0.f, a2 = 0.f, a3 = 0.f;
    const unsigned* hr = h + (size_t)r * DH;
    for (int k = 0; k < DH; ++k) {
        unsigned wd = hr[k];
        float hvv = bf16_to_f32((short)(wd & 0xffffu)) + bf16_to_f32((short)(wd >> 16));
        const float* w = Wph + (size_t)k * NCLS;
        a0 += hvv * w[tid];
        a1 += hvv * w[tid + 256];
        a2 += hvv * w[tid + 512];
        a3 += hvv * w[tid + 768];
    }
    a0 += bP[tid]; a1 += bP[tid + 256]; a2 += bP[tid + 512]; a3 += bP[tid + 768];

    float m = fmaxf(fmaxf(a0, a1), fmaxf(a2, a3));
    red[tid] = m; __syncthreads();
    for (int s = 128; s > 0; s >>= 1) {
        if (tid < s) red[tid] = fmaxf(red[tid], red[tid + s]);
        __syncthreads();
    }
    m = red[0];
    __syncthreads();

    float e0 = expf(a0 - m), e1 = expf(a1 - m), e2 = expf(a2 - m), e3 = expf(a3 - m);
    red[tid] = e0 + e1 + e2 + e3; __syncthreads();
    for (int s = 128; s > 0; s >>= 1) {
        if (tid < s) red[tid] += red[tid + s];
        __syncthreads();
    }
    const float inv = 1.0f / red[0];

    float* o = out + (size_t)r * NCLS;
    o[tid]       = e0 * inv;
    o[tid + 256] = e1 * inv;
    o[tid + 512] = e2 * inv;
    o[tid + 768] = e3 * inv;
}

// ---------------------------------------------------------------------------
extern "C" void kernel_launch(void* const* d_in, const int* in_sizes, int n_in,
                              void* d_out, int out_size, void* d_ws, size_t ws_size,
                              hipStream_t stream)
{
    const float* x   = (const float*)d_in[0];
    const float* Wgx = (const float*)d_in[1];
    const float* Wgh = (const float*)d_in[2];
    const float* bg  = (const float*)d_in[3];
    const float* Wix = (const float*)d_in[4];
    const float* Wih = (const float*)d_in[5];
    const float* bi  = (const float*)d_in[6];
    const float* Wfx = (const float*)d_in[7];
    const float* Wfh = (const float*)d_in[8];
    const float* bf  = (const float*)d_in[9];
    const float* Wox = (const float*)d_in[10];
    const float* Woh = (const float*)d_in[11];
    const float* bo  = (const float*)d_in[12];
    const float* Wph = (const float*)d_in[13];
    const float* bP  = (const float*)d_in[14];

    char* ws = (char*)d_ws;
    short* Wb_hi   = (short*)ws;                             // [2048][768] bf16
    short* Wb_lo   = Wb_hi + (size_t)NG * KTOT;              // [2048][768] bf16
    float* bp      = (float*)(Wb_lo + (size_t)NG * KTOT);    // [2048]
    unsigned* hp0  = (unsigned*)(bp + NG);                   // [256][512] packed bf16 pair
    unsigned* hp1  = hp0 + (size_t)BATCH * DH;
    unsigned* bar  = hp1 + (size_t)BATCH * DH;               // 16 ctrs + xcd table + init ctr

    pack_kernel<<<(KTOT * NG + 255) / 256, 256, 0, stream>>>(
        Wgx, Wgh, Wix, Wih, Wfx, Wfh, Wox, Woh, bg, bi, bf, bo,
        Wb_hi, Wb_lo, bp, hp0, bar);

    void* args[] = {(void*)&x, (void*)&Wb_hi, (void*)&Wb_lo, (void*)&bp,
                    (void*)&hp0, (void*)&hp1, (void*)&bar};
    hipLaunchCooperativeKernel((void*)lstm_main, dim3(256), dim3(NTH), args,
                               0, stream);

    // 512 steps -> final h is in hp0
    proj_softmax<<<BATCH, 256, 0, stream>>>(hp0, Wph, bP, (float*)d_out);
}

// Round 9
// 1813.688 us; speedup vs baseline: 25.1267x; 1.0283x over previous
//
#include <hip/hip_runtime.h>
#include <hip/hip_bf16.h>

typedef __attribute__((ext_vector_type(4))) float f32x4;
typedef __attribute__((ext_vector_type(8))) short s16x8;   // 8 bf16 (4 VGPR) mfma frag
typedef __attribute__((ext_vector_type(4))) short s16x4;   // 4 bf16 (8B)

#define BATCH 256
#define SEQL  512
#define DIN   256
#define DH    512
#define NG    2048   // 4*DH, gate-interleaved: n = 4*unit + gate (0=g,1=i,2=f,3=o)
#define KTOT  768
#define NKT   24     // total k-tiles of 32 (8 x-tiles + 16 h-tiles)
#define NCLS  1024
#define NTH   512
#define ROWS  16     // batch rows per block
#define COLS  128    // gate cols per block
#define XSTR  264    // x-plane row stride (shorts)
#define HSTR  520    // h-plane row stride (shorts)

// bf16 RNE from f32, bit-twiddle (finite inputs)
__device__ __forceinline__ short bf16_rne(float a) {
    union { float f; unsigned u; } ua; ua.f = a;
    unsigned r = (ua.u + 0x7FFFu + ((ua.u >> 16) & 1u)) >> 16;
    return (short)r;
}
__device__ __forceinline__ float bf16_to_f32(short b) {
    union { unsigned u; float f; } v; v.u = ((unsigned)(unsigned short)b) << 16;
    return v.f;
}

// fast activations: v_exp_f32 + v_rcp_f32 (~1ulp each; saturates correctly at +-inf)
__device__ __forceinline__ float fast_sigmoid(float z) {
    return __builtin_amdgcn_rcpf(1.0f + __expf(-z));
}
__device__ __forceinline__ float fast_tanh(float z) {
    return 1.0f - 2.0f * __builtin_amdgcn_rcpf(__expf(2.0f * z) + 1.0f);
}

// ---------------------------------------------------------------------------
// Pack W into hi/lo bf16 planes, n-major k-contiguous: Wb[n][k]. Pack biases.
// Zero packed-h buffers (both parities) and barrier/init state.
// ---------------------------------------------------------------------------
__global__ void pack_kernel(const float* __restrict__ Wgx, const float* __restrict__ Wgh,
                            const float* __restrict__ Wix, const float* __restrict__ Wih,
                            const float* __restrict__ Wfx, const float* __restrict__ Wfh,
                            const float* __restrict__ Wox, const float* __restrict__ Woh,
                            const float* __restrict__ bg,  const float* __restrict__ bi,
                            const float* __restrict__ bf,  const float* __restrict__ bo,
                            short* __restrict__ Wb_hi, short* __restrict__ Wb_lo,
                            float* __restrict__ bp, unsigned* __restrict__ hp,
                            unsigned* __restrict__ bar)
{
    int idx = blockIdx.x * blockDim.x + threadIdx.x;
    if (idx < KTOT * NG) {
        int n = idx / KTOT;
        int k = idx - n * KTOT;
        int unit = n >> 2;
        int gate = n & 3;
        float v;
        if (k < DIN) {
            const float* src = (gate == 0) ? Wgx : (gate == 1) ? Wix : (gate == 2) ? Wfx : Wox;
            v = src[k * DH + unit];
        } else {
            const float* src = (gate == 0) ? Wgh : (gate == 1) ? Wih : (gate == 2) ? Wfh : Woh;
            v = src[(k - DIN) * DH + unit];
        }
        short hi = bf16_rne(v);
        short lo = bf16_rne(v - bf16_to_f32(hi));
        Wb_hi[idx] = hi;
        Wb_lo[idx] = lo;
    }
    if (idx < NG) {
        int unit = idx >> 2;
        int gate = idx & 3;
        const float* bsrc = (gate == 0) ? bg : (gate == 1) ? bi : (gate == 2) ? bf : bo;
        bp[idx] = bsrc[unit];
    }
    if (idx < 2 * BATCH * DH) hp[idx] = 0u;   // both h parities (packed bf16 pair, 0 == 0.0)
    if (idx < 1024) bar[idx] = 0u;            // barrier ctrs + xcd table + init ctr
}

// ---------------------------------------------------------------------------
// Persistent split-bf16 MFMA LSTM. 256 blocks x 512 threads.
// Group mapping rt=bid&15 -> 16 group-blocks share one XCD (round-robin
// dispatch); runtime-verified via HW_REG_XCC_ID, agent-scope fallback else.
// Local mode: h plain-store -> XCD L2; h-load sc0 (L1-bypass); ctr RMW at
// workgroup scope (local L2). Step schedule (r9: x-prefetch moved to TOP):
//   stage x -> sync(a) -> ISSUE x-prefetch(t+1) -> x-MFMA (8kt)
//   poll(ctr>=16t) -> sync -> h-load/stage -> sync(b) -> h-MFMA (16kt)
//   act -> h-store -> vmcnt(0) [prefetch long done] -> sync(c) -> arrive
// ---------------------------------------------------------------------------
__global__ __launch_bounds__(NTH, 2) void lstm_main(
    const float* __restrict__ x, const short* __restrict__ Wb_hi,
    const short* __restrict__ Wb_lo, const float* __restrict__ bp,
    unsigned* __restrict__ hp0, unsigned* __restrict__ hp1,
    unsigned* __restrict__ bar)
{
    __shared__ short Xlds[2][ROWS][XSTR];   // hi/lo planes, x part (k 0..255)
    __shared__ short Hlds[2][ROWS][HSTR];   // hi/lo planes, h part (k 256..767)
    __shared__ unsigned mode_sh;

    const int tid = threadIdx.x;
    const int bid = blockIdx.x;
    const int rt = bid & 15;                // row-group 0..15  (XCD-local mapping)
    const int ct = bid >> 4;                // col tile 0..15
    const int r0 = rt * ROWS;
    const int n0 = ct * COLS;
    const int wv = tid >> 6;                // wave 0..7
    const int l  = tid & 63;
    const int lane16 = l & 15;
    const int lq = l >> 4;                  // k-group 0..3

    // ---- init: publish XCC_ID, grid barrier, per-group locality verdict ----
    if (tid == 0) {
        unsigned xcc;
        asm volatile("s_getreg_b32 %0, hwreg(HW_REG_XCC_ID)" : "=s"(xcc));
        __hip_atomic_store(bar + 640 + bid, xcc, __ATOMIC_RELAXED, __HIP_MEMORY_SCOPE_AGENT);
        asm volatile("s_waitcnt vmcnt(0)" ::: "memory");
        __hip_atomic_fetch_add(bar + 896, 1u, __ATOMIC_RELAXED, __HIP_MEMORY_SCOPE_AGENT);
        for (;;) {
            unsigned v = __hip_atomic_fetch_add(bar + 896, 0u, __ATOMIC_RELAXED,
                                                __HIP_MEMORY_SCOPE_AGENT);
            if (v >= 256u) break;
            __builtin_amdgcn_s_sleep(4);
        }
        unsigned ok = 1;
        for (int k2 = 0; k2 < 16; ++k2) {
            unsigned other = __hip_atomic_load(bar + 640 + rt + 16 * k2,
                                               __ATOMIC_RELAXED, __HIP_MEMORY_SCOPE_AGENT);
            ok &= (other == xcc) ? 1u : 0u;
        }
        mode_sh = ok;
    }
    __syncthreads();
    const bool local_mode = (mode_sh != 0);

    // ---- W fragments to registers, once ----
    s16x8 wh[NKT], wl[NKT];
    {
        const size_t colbase = (size_t)(n0 + wv * 16 + lane16) * KTOT;
        #pragma unroll
        for (int kt = 0; kt < NKT; ++kt) {
            wh[kt] = *(const s16x8*)(Wb_hi + colbase + kt * 32 + lq * 8);
            wl[kt] = *(const s16x8*)(Wb_lo + colbase + kt * 32 + lq * 8);
        }
    }

    const float4 bias = *(const float4*)(bp + n0 + wv * 16 + 4 * lq);
    const int unit_g = (n0 >> 2) + wv * 4 + lq;

    const int srow = tid >> 5;              // staging row 0..15
    const int sl = tid & 31;

    unsigned* ctr = bar + rt * 32;          // 128B-padded per row-group

    float creg = 0.f;

    // x prologue prefetch (t=0)
    float4 xv0, xv1;
    {
        const float* xr = x + (size_t)(r0 + srow) * (SEQL * DIN);
        xv0 = *(const float4*)(xr + 4 * sl);
        xv1 = *(const float4*)(xr + 4 * sl + 128);
    }

    for (int t = 0; t < SEQL; ++t) {
        // ---- pin W frags in registers (no-op asm; blocks rematerialization) ----
        asm volatile("" : "+v"(wh[0]),"+v"(wh[1]),"+v"(wh[2]),"+v"(wh[3]),"+v"(wh[4]),"+v"(wh[5]),"+v"(wh[6]),"+v"(wh[7]),"+v"(wh[8]),"+v"(wh[9]),"+v"(wh[10]),"+v"(wh[11]));
        asm volatile("" : "+v"(wh[12]),"+v"(wh[13]),"+v"(wh[14]),"+v"(wh[15]),"+v"(wh[16]),"+v"(wh[17]),"+v"(wh[18]),"+v"(wh[19]),"+v"(wh[20]),"+v"(wh[21]),"+v"(wh[22]),"+v"(wh[23]));
        asm volatile("" : "+v"(wl[0]),"+v"(wl[1]),"+v"(wl[2]),"+v"(wl[3]),"+v"(wl[4]),"+v"(wl[5]),"+v"(wl[6]),"+v"(wl[7]),"+v"(wl[8]),"+v"(wl[9]),"+v"(wl[10]),"+v"(wl[11]));
        asm volatile("" : "+v"(wl[12]),"+v"(wl[13]),"+v"(wl[14]),"+v"(wl[15]),"+v"(wl[16]),"+v"(wl[17]),"+v"(wl[18]),"+v"(wl[19]),"+v"(wl[20]),"+v"(wl[21]),"+v"(wl[22]),"+v"(wl[23]));

        const unsigned* __restrict__ hin = (t & 1) ? hp1 : hp0;
        unsigned* __restrict__ hout      = (t & 1) ? hp0 : hp1;

        // ---- stage x_t (prefetched regs) -> LDS x planes ----
        {
            float4 v = xv0; int k0 = 4 * sl;
            #pragma unroll
            for (int i = 0; i < 2; ++i) {
                short h0b = bf16_rne(v.x), h1b = bf16_rne(v.y);
                short h2b = bf16_rne(v.z), h3b = bf16_rne(v.w);
                s16x4 hi4 = { h0b, h1b, h2b, h3b };
                s16x4 lo4 = { bf16_rne(v.x - bf16_to_f32(h0b)),
                              bf16_rne(v.y - bf16_to_f32(h1b)),
                              bf16_rne(v.z - bf16_to_f32(h2b)),
                              bf16_rne(v.w - bf16_to_f32(h3b)) };
                *(s16x4*)(&Xlds[0][srow][k0]) = hi4;
                *(s16x4*)(&Xlds[1][srow][k0]) = lo4;
                v = xv1; k0 = 4 * sl + 128;
            }
        }
        __syncthreads();   // (a) x staged; xv regs free

        // ---- issue x-prefetch for t+1 NOW: latency hides under the whole step ----
        {
            int tn = (t + 1 < SEQL) ? t + 1 : SEQL - 1;
            const float* xr = x + (size_t)(r0 + srow) * (SEQL * DIN) + (size_t)tn * DIN;
            xv0 = *(const float4*)(xr + 4 * sl);
            xv1 = *(const float4*)(xr + 4 * sl + 128);
        }

        // ---- x-part MFMA: 8 k-tiles x 3 (overlaps other blocks' arrivals) ----
        f32x4 acc0 = {0.f, 0.f, 0.f, 0.f};
        f32x4 acc1 = {0.f, 0.f, 0.f, 0.f};
        {
            const short* ax_hi = &Xlds[0][lane16][lq * 8];
            const short* ax_lo = &Xlds[1][lane16][lq * 8];
            #pragma unroll
            for (int kt = 0; kt < 8; ++kt) {
                s16x8 a_hi = *(const s16x8*)(ax_hi + kt * 32);
                s16x8 a_lo = *(const s16x8*)(ax_lo + kt * 32);
                if (kt & 1) {
                    acc1 = __builtin_amdgcn_mfma_f32_16x16x32_bf16(wh[kt], a_hi, acc1, 0, 0, 0);
                    acc1 = __builtin_amdgcn_mfma_f32_16x16x32_bf16(wl[kt], a_hi, acc1, 0, 0, 0);
                    acc1 = __builtin_amdgcn_mfma_f32_16x16x32_bf16(wh[kt], a_lo, acc1, 0, 0, 0);
                } else {
                    acc0 = __builtin_amdgcn_mfma_f32_16x16x32_bf16(wh[kt], a_hi, acc0, 0, 0, 0);
                    acc0 = __builtin_amdgcn_mfma_f32_16x16x32_bf16(wl[kt], a_hi, acc0, 0, 0, 0);
                    acc0 = __builtin_amdgcn_mfma_f32_16x16x32_bf16(wh[kt], a_lo, acc0, 0, 0, 0);
                }
            }
        }

        // ---- wait: h_{t-1} ready (ctr >= 16*t) ----
        if (tid == 0) {
            const unsigned need = 16u * (unsigned)t;
            if (local_mode) {
                for (;;) {   // tight spin: L2-local RMW, low discovery latency
                    unsigned v = __hip_atomic_fetch_add(ctr, 0u, __ATOMIC_RELAXED,
                                                        __HIP_MEMORY_SCOPE_WORKGROUP);
                    if (v >= need) break;
                }
            } else {
                for (;;) {
                    unsigned v = __hip_atomic_fetch_add(ctr, 0u, __ATOMIC_RELAXED,
                                                        __HIP_MEMORY_SCOPE_AGENT);
                    if (v >= need) break;
                    __builtin_amdgcn_s_sleep(1);
                }
            }
        }
        __syncthreads();   // release: h data visible at this group's coherence point

        // ---- h loads ----
        unsigned long long hvl[8];
        {
            const unsigned* hrow = hin + (size_t)(r0 + srow) * DH + 2 * sl;
            if (local_mode) {
                const unsigned long long* p = (const unsigned long long*)hrow;
                #pragma unroll
                for (int j = 0; j < 8; ++j)
                    asm volatile("global_load_dwordx2 %0, %1, off sc0"
                                 : "=v"(hvl[j]) : "v"(p + 32 * j));
                asm volatile("s_waitcnt vmcnt(0)" ::: "memory");
                __builtin_amdgcn_sched_barrier(0);
            } else {
                #pragma unroll
                for (int j = 0; j < 8; ++j)
                    hvl[j] = __hip_atomic_load((const unsigned long long*)(hrow + 64 * j),
                                               __ATOMIC_RELAXED, __HIP_MEMORY_SCOPE_AGENT);
            }
        }
        // ---- h -> LDS planes (unpack hi/lo pairs with v_perm) ----
        #pragma unroll
        for (int j = 0; j < 8; ++j) {
            unsigned w0 = (unsigned)hvl[j];
            unsigned w1 = (unsigned)(hvl[j] >> 32);
            unsigned hi = __builtin_amdgcn_perm(w1, w0, 0x05040100u);
            unsigned lo = __builtin_amdgcn_perm(w1, w0, 0x07060302u);
            int k0 = 2 * sl + 64 * j;
            *(unsigned*)(&Hlds[0][srow][k0]) = hi;
            *(unsigned*)(&Hlds[1][srow][k0]) = lo;
        }
        __syncthreads();   // (b) h staged

        // ---- h-part MFMA: 16 k-tiles x 3 ----
        {
            const short* ah_hi = &Hlds[0][lane16][lq * 8];
            const short* ah_lo = &Hlds[1][lane16][lq * 8];
            #pragma unroll
            for (int kt = 8; kt < NKT; ++kt) {
                const int ko = (kt - 8) * 32;
                s16x8 a_hi = *(const s16x8*)(ah_hi + ko);
                s16x8 a_lo = *(const s16x8*)(ah_lo + ko);
                if (kt & 1) {
                    acc1 = __builtin_amdgcn_mfma_f32_16x16x32_bf16(wh[kt], a_hi, acc1, 0, 0, 0);
                    acc1 = __builtin_amdgcn_mfma_f32_16x16x32_bf16(wl[kt], a_hi, acc1, 0, 0, 0);
                    acc1 = __builtin_amdgcn_mfma_f32_16x16x32_bf16(wh[kt], a_lo, acc1, 0, 0, 0);
                } else {
                    acc0 = __builtin_amdgcn_mfma_f32_16x16x32_bf16(wh[kt], a_hi, acc0, 0, 0, 0);
                    acc0 = __builtin_amdgcn_mfma_f32_16x16x32_bf16(wl[kt], a_hi, acc0, 0, 0, 0);
                    acc0 = __builtin_amdgcn_mfma_f32_16x16x32_bf16(wh[kt], a_lo, acc0, 0, 0, 0);
                }
            }
        }

        float zg = acc0.x + acc1.x + bias.x;
        float zi = acc0.y + acc1.y + bias.y;
        float zf = acc0.z + acc1.z + bias.z;
        float zo = acc0.w + acc1.w + bias.w;

        float gv = fast_sigmoid(zg);   // sigmoid on g (reference quirk)
        float iv = fast_tanh(zi);
        float fv = fast_tanh(zf);
        float ov = fast_tanh(zo);
        creg = gv * iv + creg * fv;
        float hv = fast_tanh(creg) * ov;

        // ---- pack h -> u32 (bf16 hi | lo<<16) and store ----
        {
            short hh = bf16_rne(hv);
            short hlo = bf16_rne(hv - bf16_to_f32(hh));
            unsigned word = (unsigned)(unsigned short)hh |
                            ((unsigned)(unsigned short)hlo << 16);
            unsigned* dst = hout + (size_t)(r0 + lane16) * DH + unit_g;
            if (local_mode) {
                *dst = word;                               // plain store -> XCD L2
            } else {
                __hip_atomic_store(dst, word, __ATOMIC_RELAXED, __HIP_MEMORY_SCOPE_AGENT);
            }
        }

        asm volatile("s_waitcnt vmcnt(0)" ::: "memory");   // h stores complete (prefetch long done)
        __syncthreads();                                   // (c) all waves drained
        // ---- arrive ----
        if (tid == 0) {
            if (local_mode)
                __hip_atomic_fetch_add(ctr, 1u, __ATOMIC_RELAXED, __HIP_MEMORY_SCOPE_WORKGROUP);
            else
                __hip_atomic_fetch_add(ctr, 1u, __ATOMIC_RELAXED, __HIP_MEMORY_SCOPE_AGENT);
        }
    }
}

// ---------------------------------------------------------------------------
// Final projection + softmax, fused. One block per batch row. h is packed
// bf16 hi/lo u32; reconstruct f32 = hi + lo.
// ---------------------------------------------------------------------------
__global__ __launch_bounds__(256) void proj_softmax(
    const unsigned* __restrict__ h, const float* __restrict__ Wph,
    const float* __restrict__ bP, float* __restrict__ out)
{
    __shared__ float red[256];
    const int r = blockIdx.x;
    const int tid = threadIdx.x;
    float a0 = 0.f, a1 = 0.f, a2 = 0.f, a3 = 0.f;
    const unsigned* hr = h + (size_t)r * DH;
    for (int k = 0; k < DH; ++k) {
        unsigned wd = hr[k];
        float hvv = bf16_to_f32((short)(wd & 0xffffu)) + bf16_to_f32((short)(wd >> 16));
        const float* w = Wph + (size_t)k * NCLS;
        a0 += hvv * w[tid];
        a1 += hvv * w[tid + 256];
        a2 += hvv * w[tid + 512];
        a3 += hvv * w[tid + 768];
    }
    a0 += bP[tid]; a1 += bP[tid + 256]; a2 += bP[tid + 512]; a3 += bP[tid + 768];

    float m = fmaxf(fmaxf(a0, a1), fmaxf(a2, a3));
    red[tid] = m; __syncthreads();
    for (int s = 128; s > 0; s >>= 1) {
        if (tid < s) red[tid] = fmaxf(red[tid], red[tid + s]);
        __syncthreads();
    }
    m = red[0];
    __syncthreads();

    float e0 = expf(a0 - m), e1 = expf(a1 - m), e2 = expf(a2 - m), e3 = expf(a3 - m);
    red[tid] = e0 + e1 + e2 + e3; __syncthreads();
    for (int s = 128; s > 0; s >>= 1) {
        if (tid < s) red[tid] += red[tid + s];
        __syncthreads();
    }
    const float inv = 1.0f / red[0];

    float* o = out + (size_t)r * NCLS;
    o[tid]       = e0 * inv;
    o[tid + 256] = e1 * inv;
    o[tid + 512] = e2 * inv;
    o[tid + 768] = e3 * inv;
}

// ---------------------------------------------------------------------------
extern "C" void kernel_launch(void* const* d_in, const int* in_sizes, int n_in,
                              void* d_out, int out_size, void* d_ws, size_t ws_size,
                              hipStream_t stream)
{
    const float* x   = (const float*)d_in[0];
    const float* Wgx = (const float*)d_in[1];
    const float* Wgh = (const float*)d_in[2];
    const float* bg  = (const float*)d_in[3];
    const float* Wix = (const float*)d_in[4];
    const float* Wih = (const float*)d_in[5];
    const float* bi  = (const float*)d_in[6];
    const float* Wfx = (const float*)d_in[7];
    const float* Wfh = (const float*)d_in[8];
    const float* bf  = (const float*)d_in[9];
    const float* Wox = (const float*)d_in[10];
    const float* Woh = (const float*)d_in[11];
    const float* bo  = (const float*)d_in[12];
    const float* Wph = (const float*)d_in[13];
    const float* bP  = (const float*)d_in[14];

    char* ws = (char*)d_ws;
    short* Wb_hi   = (short*)ws;                             // [2048][768] bf16
    short* Wb_lo   = Wb_hi + (size_t)NG * KTOT;              // [2048][768] bf16
    float* bp      = (float*)(Wb_lo + (size_t)NG * KTOT);    // [2048]
    unsigned* hp0  = (unsigned*)(bp + NG);                   // [256][512] packed bf16 pair
    unsigned* hp1  = hp0 + (size_t)BATCH * DH;
    unsigned* bar  = hp1 + (size_t)BATCH * DH;               // 16 ctrs + xcd table + init ctr

    pack_kernel<<<(KTOT * NG + 255) / 256, 256, 0, stream>>>(
        Wgx, Wgh, Wix, Wih, Wfx, Wfh, Wox, Woh, bg, bi, bf, bo,
        Wb_hi, Wb_lo, bp, hp0, bar);

    void* args[] = {(void*)&x, (void*)&Wb_hi, (void*)&Wb_lo, (void*)&bp,
                    (void*)&hp0, (void*)&hp1, (void*)&bar};
    hipLaunchCooperativeKernel((void*)lstm_main, dim3(256), dim3(NTH), args,
                               0, stream);

    // 512 steps -> final h is in hp0
    proj_softmax<<<BATCH, 256, 0, stream>>>(hp0, Wph, bP, (float*)d_out);
}

// Round 11
// 1354.520 us; speedup vs baseline: 33.6444x; 1.3390x over previous
//
#include <hip/hip_runtime.h>
#include <hip/hip_bf16.h>

typedef __attribute__((ext_vector_type(4))) float f32x4;
typedef __attribute__((ext_vector_type(8))) short s16x8;   // 8 bf16 (4 VGPR) mfma frag
typedef __attribute__((ext_vector_type(4))) short s16x4;   // 4 bf16 (8B)
typedef __attribute__((ext_vector_type(4))) unsigned u32x4; // 16B load/store tuple

#define BATCH 256
#define SEQL  512
#define DIN   256
#define DH    512
#define NG    2048   // 4*DH, gate-interleaved: n = 4*unit + gate (0=g,1=i,2=f,3=o)
#define KTOT  768
#define NKT   24     // 8 x-kt (3 MFMA each) + 16 h-kt (2 MFMA each)
#define NCLS  1024
#define NTH   512
#define ROWS  16
#define COLS  128
#define XSTR  264    // x-plane row stride (shorts): 132 words == 4 mod 32
#define HSTR  520    // h-plane row stride (shorts): 260 words == 4 mod 32

// bf16 RNE from f32, bit-twiddle (finite inputs)
__device__ __forceinline__ short bf16_rne(float a) {
    union { float f; unsigned u; } ua; ua.f = a;
    unsigned r = (ua.u + 0x7FFFu + ((ua.u >> 16) & 1u)) >> 16;
    return (short)r;
}
__device__ __forceinline__ float bf16_to_f32(short b) {
    union { unsigned u; float f; } v; v.u = ((unsigned)(unsigned short)b) << 16;
    return v.f;
}
__device__ __forceinline__ float fast_sigmoid(float z) {
    return __builtin_amdgcn_rcpf(1.0f + __expf(-z));
}
__device__ __forceinline__ float fast_tanh(float z) {
    return 1.0f - 2.0f * __builtin_amdgcn_rcpf(__expf(2.0f * z) + 1.0f);
}

// ---------------------------------------------------------------------------
// Pack W into hi/lo bf16 planes [n][k] (n gate-interleaved). Pack biases.
// Zero h buffers (both parities, plain bf16) and barrier/init state.
// ---------------------------------------------------------------------------
__global__ void pack_kernel(const float* __restrict__ Wgx, const float* __restrict__ Wgh,
                            const float* __restrict__ Wix, const float* __restrict__ Wih,
                            const float* __restrict__ Wfx, const float* __restrict__ Wfh,
                            const float* __restrict__ Wox, const float* __restrict__ Woh,
                            const float* __restrict__ bg,  const float* __restrict__ bi,
                            const float* __restrict__ bf,  const float* __restrict__ bo,
                            short* __restrict__ Wb_hi, short* __restrict__ Wb_lo,
                            float* __restrict__ bp, unsigned* __restrict__ hp,
                            unsigned* __restrict__ bar)
{
    int idx = blockIdx.x * blockDim.x + threadIdx.x;
    if (idx < KTOT * NG) {
        int n = idx / KTOT;
        int k = idx - n * KTOT;
        int unit = n >> 2;
        int gate = n & 3;
        float v;
        if (k < DIN) {
            const float* src = (gate == 0) ? Wgx : (gate == 1) ? Wix : (gate == 2) ? Wfx : Wox;
            v = src[k * DH + unit];
        } else {
            const float* src = (gate == 0) ? Wgh : (gate == 1) ? Wih : (gate == 2) ? Wfh : Woh;
            v = src[(k - DIN) * DH + unit];
        }
        short hi = bf16_rne(v);
        short lo = bf16_rne(v - bf16_to_f32(hi));
        Wb_hi[idx] = hi;
        Wb_lo[idx] = lo;
    }
    if (idx < NG) {
        int unit = idx >> 2;
        int gate = idx & 3;
        const float* bsrc = (gate == 0) ? bg : (gate == 1) ? bi : (gate == 2) ? bf : bo;
        bp[idx] = bsrc[unit];
    }
    if (idx < (2 * BATCH * DH) / 2) hp[idx] = 0u;   // 2 parities x 256x512 bf16
    if (idx < 1024) bar[idx] = 0u;
}

// ---------------------------------------------------------------------------
// Persistent MFMA LSTM — r9 structure (proven), h-datapath slimmed:
// h is PLAIN bf16 (x stays split hi/lo, W split hi/lo pinned in 192 regs).
// Per wave/step: 8 x-kt x 3 MFMA + 16 h-kt x 2 MFMA = 56 MFMA, 32 b128 LDS
// reads (was 72 / 48). h staged: 2x global_load_dwordx4 (sc0) + 2x b128
// ds_write per thread (was 8 loads + 16 perms + 16 ds_writes).
// Group mapping rt=bid&15 -> 16 blocks share an XCD (runtime-verified via
// HW_REG_XCC_ID; agent-scope fallback else). Barrier: per-group monotonic ctr,
// tid0 arrive (need=16t), relaxed RMW polls, s_sleep(1) in all spins.
// Step: stage x -> sync(a) -> issue x-prefetch(t+1) -> x-MFMA -> poll -> sync
//       -> h-load/stage -> sync(b) -> h-MFMA -> act -> h-store -> vmcnt(0)
//       -> sync(c) -> arrive.
// ---------------------------------------------------------------------------
__global__ __launch_bounds__(NTH, 2) void lstm_main(
    const float* __restrict__ x, const short* __restrict__ Wb_hi,
    const short* __restrict__ Wb_lo, const float* __restrict__ bp,
    short* __restrict__ hp, unsigned* __restrict__ bar)
{
    __shared__ short Xlds[2][ROWS][XSTR];   // hi/lo planes, x part
    __shared__ short Hlds[ROWS][HSTR];      // plain bf16 h
    __shared__ unsigned mode_sh;

    const int tid = threadIdx.x;
    const int bid = blockIdx.x;
    const int rt = bid & 15;                // row-group (XCD-local mapping)
    const int ct = bid >> 4;
    const int r0 = rt * ROWS;
    const int n0 = ct * COLS;
    const int wv = tid >> 6;                // wave 0..7
    const int l  = tid & 63;
    const int lane16 = l & 15;
    const int lq = l >> 4;                  // k-group 0..3

    // ---- init: publish XCC_ID, grid barrier, per-group locality verdict ----
    if (tid == 0) {
        unsigned xcc;
        asm volatile("s_getreg_b32 %0, hwreg(HW_REG_XCC_ID)" : "=s"(xcc));
        __hip_atomic_store(bar + 640 + bid, xcc, __ATOMIC_RELAXED, __HIP_MEMORY_SCOPE_AGENT);
        asm volatile("s_waitcnt vmcnt(0)" ::: "memory");
        __hip_atomic_fetch_add(bar + 896, 1u, __ATOMIC_RELAXED, __HIP_MEMORY_SCOPE_AGENT);
        for (;;) {
            unsigned v = __hip_atomic_fetch_add(bar + 896, 0u, __ATOMIC_RELAXED,
                                                __HIP_MEMORY_SCOPE_AGENT);
            if (v >= 256u) break;
            __builtin_amdgcn_s_sleep(4);
        }
        unsigned ok = 1;
        for (int k2 = 0; k2 < 16; ++k2) {
            unsigned other = __hip_atomic_load(bar + 640 + rt + 16 * k2,
                                               __ATOMIC_RELAXED, __HIP_MEMORY_SCOPE_AGENT);
            ok &= (other == xcc) ? 1u : 0u;
        }
        mode_sh = ok;
    }
    __syncthreads();
    const bool local_mode = (mode_sh != 0);

    // ---- W fragments to registers, once ----
    s16x8 wh[NKT], wl[NKT];
    {
        const size_t colbase = (size_t)(n0 + wv * 16 + lane16) * KTOT;
        #pragma unroll
        for (int kt = 0; kt < NKT; ++kt) {
            wh[kt] = *(const s16x8*)(Wb_hi + colbase + kt * 32 + lq * 8);
            wl[kt] = *(const s16x8*)(Wb_lo + colbase + kt * 32 + lq * 8);
        }
    }

    const float4 bias = *(const float4*)(bp + n0 + wv * 16 + 4 * lq);
    const int unit_g = (n0 >> 2) + wv * 4 + lq;

    const int srow = tid >> 5;              // staging row 0..15
    const int sl = tid & 31;                // 0..31

    unsigned* ctr = bar + rt * 32;          // 128B-padded per row-group

    float creg = 0.f;

    // x prologue prefetch (t=0)
    float4 xv0, xv1;
    {
        const float* xr = x + (size_t)(r0 + srow) * (SEQL * DIN);
        xv0 = *(const float4*)(xr + 4 * sl);
        xv1 = *(const float4*)(xr + 4 * sl + 128);
    }

    for (int t = 0; t < SEQL; ++t) {
        // ---- pin W frags in registers (no-op asm; blocks rematerialization) ----
        asm volatile("" : "+v"(wh[0]),"+v"(wh[1]),"+v"(wh[2]),"+v"(wh[3]),"+v"(wh[4]),"+v"(wh[5]),"+v"(wh[6]),"+v"(wh[7]),"+v"(wh[8]),"+v"(wh[9]),"+v"(wh[10]),"+v"(wh[11]));
        asm volatile("" : "+v"(wh[12]),"+v"(wh[13]),"+v"(wh[14]),"+v"(wh[15]),"+v"(wh[16]),"+v"(wh[17]),"+v"(wh[18]),"+v"(wh[19]),"+v"(wh[20]),"+v"(wh[21]),"+v"(wh[22]),"+v"(wh[23]));
        asm volatile("" : "+v"(wl[0]),"+v"(wl[1]),"+v"(wl[2]),"+v"(wl[3]),"+v"(wl[4]),"+v"(wl[5]),"+v"(wl[6]),"+v"(wl[7]),"+v"(wl[8]),"+v"(wl[9]),"+v"(wl[10]),"+v"(wl[11]));
        asm volatile("" : "+v"(wl[12]),"+v"(wl[13]),"+v"(wl[14]),"+v"(wl[15]),"+v"(wl[16]),"+v"(wl[17]),"+v"(wl[18]),"+v"(wl[19]),"+v"(wl[20]),"+v"(wl[21]),"+v"(wl[22]),"+v"(wl[23]));

        const short* __restrict__ hin = hp + (size_t)(t & 1) * (BATCH * DH);
        short* __restrict__ hout      = hp + (size_t)((t + 1) & 1) * (BATCH * DH);

        // ---- stage x_t (prefetched regs) -> LDS x planes ----
        {
            float4 v = xv0; int k0 = 4 * sl;
            #pragma unroll
            for (int i = 0; i < 2; ++i) {
                short h0b = bf16_rne(v.x), h1b = bf16_rne(v.y);
                short h2b = bf16_rne(v.z), h3b = bf16_rne(v.w);
                s16x4 hi4 = { h0b, h1b, h2b, h3b };
                s16x4 lo4 = { bf16_rne(v.x - bf16_to_f32(h0b)),
                              bf16_rne(v.y - bf16_to_f32(h1b)),
                              bf16_rne(v.z - bf16_to_f32(h2b)),
                              bf16_rne(v.w - bf16_to_f32(h3b)) };
                *(s16x4*)(&Xlds[0][srow][k0]) = hi4;
                *(s16x4*)(&Xlds[1][srow][k0]) = lo4;
                v = xv1; k0 = 4 * sl + 128;
            }
        }
        __syncthreads();   // (a) x staged; xv regs free

        // ---- issue x-prefetch for t+1: latency hides under the whole step ----
        {
            int tn = (t + 1 < SEQL) ? t + 1 : SEQL - 1;
            const float* xr = x + (size_t)(r0 + srow) * (SEQL * DIN) + (size_t)tn * DIN;
            xv0 = *(const float4*)(xr + 4 * sl);
            xv1 = *(const float4*)(xr + 4 * sl + 128);
        }

        // ---- x-part MFMA: 8 k-tiles x 3 (overlaps other blocks' arrivals) ----
        f32x4 acc0 = {0.f, 0.f, 0.f, 0.f};
        f32x4 acc1 = {0.f, 0.f, 0.f, 0.f};
        {
            const short* ax_hi = &Xlds[0][lane16][lq * 8];
            const short* ax_lo = &Xlds[1][lane16][lq * 8];
            #pragma unroll
            for (int kt = 0; kt < 8; ++kt) {
                s16x8 a_hi = *(const s16x8*)(ax_hi + kt * 32);
                s16x8 a_lo = *(const s16x8*)(ax_lo + kt * 32);
                if (kt & 1) {
                    acc1 = __builtin_amdgcn_mfma_f32_16x16x32_bf16(wh[kt], a_hi, acc1, 0, 0, 0);
                    acc1 = __builtin_amdgcn_mfma_f32_16x16x32_bf16(wl[kt], a_hi, acc1, 0, 0, 0);
                    acc1 = __builtin_amdgcn_mfma_f32_16x16x32_bf16(wh[kt], a_lo, acc1, 0, 0, 0);
                } else {
                    acc0 = __builtin_amdgcn_mfma_f32_16x16x32_bf16(wh[kt], a_hi, acc0, 0, 0, 0);
                    acc0 = __builtin_amdgcn_mfma_f32_16x16x32_bf16(wl[kt], a_hi, acc0, 0, 0, 0);
                    acc0 = __builtin_amdgcn_mfma_f32_16x16x32_bf16(wh[kt], a_lo, acc0, 0, 0, 0);
                }
            }
        }

        // ---- wait: h_{t-1} ready (ctr >= 16*t) ----
        if (tid == 0) {
            const unsigned need = 16u * (unsigned)t;
            if (local_mode) {
                for (;;) {
                    unsigned v = __hip_atomic_fetch_add(ctr, 0u, __ATOMIC_RELAXED,
                                                        __HIP_MEMORY_SCOPE_WORKGROUP);
                    if (v >= need) break;
                    __builtin_amdgcn_s_sleep(1);
                }
            } else {
                for (;;) {
                    unsigned v = __hip_atomic_fetch_add(ctr, 0u, __ATOMIC_RELAXED,
                                                        __HIP_MEMORY_SCOPE_AGENT);
                    if (v >= need) break;
                    __builtin_amdgcn_s_sleep(1);
                }
            }
        }
        __syncthreads();   // release: h data visible at this group's coherence point

        // ---- h load: 2x dwordx4 per thread (32B of row srow) ----
        {
            u32x4 hv0, hv1;
            const short* hrow = hin + (size_t)(r0 + srow) * DH + sl * 16;
            if (local_mode) {
                asm volatile("global_load_dwordx4 %0, %2, off sc0\n\t"
                             "global_load_dwordx4 %1, %3, off sc0"
                             : "=&v"(hv0), "=&v"(hv1)
                             : "v"(hrow), "v"(hrow + 8));
            } else {
                asm volatile("global_load_dwordx4 %0, %2, off sc0 sc1\n\t"
                             "global_load_dwordx4 %1, %3, off sc0 sc1"
                             : "=&v"(hv0), "=&v"(hv1)
                             : "v"(hrow), "v"(hrow + 8));
            }
            asm volatile("s_waitcnt vmcnt(0)" ::: "memory");
            __builtin_amdgcn_sched_barrier(0);
            *(u32x4*)(&Hlds[srow][sl * 16])     = hv0;
            *(u32x4*)(&Hlds[srow][sl * 16 + 8]) = hv1;
        }
        __syncthreads();   // (b) h staged

        // ---- h-part MFMA: 16 k-tiles x 2 ----
        {
            const short* ah = &Hlds[lane16][lq * 8];
            #pragma unroll
            for (int kt = 8; kt < NKT; ++kt) {
                const int ko = (kt - 8) * 32;
                s16x8 a = *(const s16x8*)(ah + ko);
                if (kt & 1) {
                    acc1 = __builtin_amdgcn_mfma_f32_16x16x32_bf16(wh[kt], a, acc1, 0, 0, 0);
                    acc1 = __builtin_amdgcn_mfma_f32_16x16x32_bf16(wl[kt], a, acc1, 0, 0, 0);
                } else {
                    acc0 = __builtin_amdgcn_mfma_f32_16x16x32_bf16(wh[kt], a, acc0, 0, 0, 0);
                    acc0 = __builtin_amdgcn_mfma_f32_16x16x32_bf16(wl[kt], a, acc0, 0, 0, 0);
                }
            }
        }

        float zg = acc0.x + acc1.x + bias.x;
        float zi = acc0.y + acc1.y + bias.y;
        float zf = acc0.z + acc1.z + bias.z;
        float zo = acc0.w + acc1.w + bias.w;

        float gv = fast_sigmoid(zg);   // sigmoid on g (reference quirk)
        float iv = fast_tanh(zi);
        float fv = fast_tanh(zf);
        float ov = fast_tanh(zo);
        creg = gv * iv + creg * fv;
        float hv = fast_tanh(creg) * ov;

        // ---- store h (plain bf16) ----
        {
            short hb = bf16_rne(hv);
            short* dst = hout + (size_t)(r0 + lane16) * DH + unit_g;
            if (local_mode) {
                *dst = hb;                                  // plain store -> XCD L2
            } else {
                asm volatile("global_store_short %0, %1, off sc0 sc1"
                             :: "v"(dst), "v"((unsigned)(unsigned short)hb) : "memory");
            }
        }

        asm volatile("s_waitcnt vmcnt(0)" ::: "memory");   // h stores + x-prefetch drained
        __syncthreads();                                   // (c) all waves drained
        // ---- arrive ----
        if (tid == 0) {
            if (local_mode)
                __hip_atomic_fetch_add(ctr, 1u, __ATOMIC_RELAXED, __HIP_MEMORY_SCOPE_WORKGROUP);
            else
                __hip_atomic_fetch_add(ctr, 1u, __ATOMIC_RELAXED, __HIP_MEMORY_SCOPE_AGENT);
        }
    }
}

// ---------------------------------------------------------------------------
// Final projection + softmax. h is plain bf16, linear layout.
// ---------------------------------------------------------------------------
__global__ __launch_bounds__(256) void proj_softmax(
    const short* __restrict__ h, const float* __restrict__ Wph,
    const float* __restrict__ bP, float* __restrict__ out)
{
    __shared__ float red[256];
    const int r = blockIdx.x;
    const int tid = threadIdx.x;
    float a0 = 0.f, a1 = 0.f, a2 = 0.f, a3 = 0.f;
    const short* hr = h + (size_t)r * DH;
    for (int k = 0; k < DH; ++k) {
        float hvv = bf16_to_f32(hr[k]);
        const float* w = Wph + (size_t)k * NCLS;
        a0 += hvv * w[tid];
        a1 += hvv * w[tid + 256];
        a2 += hvv * w[tid + 512];
        a3 += hvv * w[tid + 768];
    }
    a0 += bP[tid]; a1 += bP[tid + 256]; a2 += bP[tid + 512]; a3 += bP[tid + 768];

    float m = fmaxf(fmaxf(a0, a1), fmaxf(a2, a3));
    red[tid] = m; __syncthreads();
    for (int s = 128; s > 0; s >>= 1) {
        if (tid < s) red[tid] = fmaxf(red[tid], red[tid + s]);
        __syncthreads();
    }
    m = red[0];
    __syncthreads();

    float e0 = expf(a0 - m), e1 = expf(a1 - m), e2 = expf(a2 - m), e3 = expf(a3 - m);
    red[tid] = e0 + e1 + e2 + e3; __syncthreads();
    for (int s = 128; s > 0; s >>= 1) {
        if (tid < s) red[tid] += red[tid + s];
        __syncthreads();
    }
    const float inv = 1.0f / red[0];

    float* o = out + (size_t)r * NCLS;
    o[tid]       = e0 * inv;
    o[tid + 256] = e1 * inv;
    o[tid + 512] = e2 * inv;
    o[tid + 768] = e3 * inv;
}

// ---------------------------------------------------------------------------
extern "C" void kernel_launch(void* const* d_in, const int* in_sizes, int n_in,
                              void* d_out, int out_size, void* d_ws, size_t ws_size,
                              hipStream_t stream)
{
    const float* x   = (const float*)d_in[0];
    const float* Wgx = (const float*)d_in[1];
    const float* Wgh = (const float*)d_in[2];
    const float* bg  = (const float*)d_in[3];
    const float* Wix = (const float*)d_in[4];
    const float* Wih = (const float*)d_in[5];
    const float* bi  = (const float*)d_in[6];
    const float* Wfx = (const float*)d_in[7];
    const float* Wfh = (const float*)d_in[8];
    const float* bf  = (const float*)d_in[9];
    const float* Wox = (const float*)d_in[10];
    const float* Woh = (const float*)d_in[11];
    const float* bo  = (const float*)d_in[12];
    const float* Wph = (const float*)d_in[13];
    const float* bP  = (const float*)d_in[14];

    char* ws = (char*)d_ws;
    short* Wb_hi   = (short*)ws;                             // [2048][768] bf16
    short* Wb_lo   = Wb_hi + (size_t)NG * KTOT;              // [2048][768] bf16
    float* bp      = (float*)(Wb_lo + (size_t)NG * KTOT);    // [2048]
    short* hp      = (short*)(bp + NG);                      // [2][256][512] bf16
    unsigned* bar  = (unsigned*)(hp + (size_t)2 * BATCH * DH);

    pack_kernel<<<(KTOT * NG + 255) / 256, 256, 0, stream>>>(
        Wgx, Wgh, Wix, Wih, Wfx, Wfh, Wox, Woh, bg, bi, bf, bo,
        Wb_hi, Wb_lo, bp, (unsigned*)hp, bar);

    void* args[] = {(void*)&x, (void*)&Wb_hi, (void*)&Wb_lo, (void*)&bp,
                    (void*)&hp, (void*)&bar};
    hipLaunchCooperativeKernel((void*)lstm_main, dim3(256), dim3(NTH), args,
                               0, stream);

    // 512 steps -> final h is in parity 0 (hp base)
    proj_softmax<<<BATCH, 256, 0, stream>>>(hp, Wph, bP, (float*)d_out);
}